// Round 12
// baseline (3512.844 us; speedup 1.0000x reference)
//
#include <hip/hip_runtime.h>
#include <hip/hip_bf16.h>

typedef __hip_bfloat16 bf16;
typedef __attribute__((ext_vector_type(8))) short short8v;   // 8 bf16 (4 VGPR)
typedef __attribute__((ext_vector_type(4))) float float4v;   // MFMA acc

// ---------------- layouts ----------------
// Tile layouts (bf16, XOR-swizzled channel dim, batch=2048 in 32 blocks of 64):
//  t1T/h1T: [pix 196][cb 32][col 64][ch 64]   elem ((pix*32+cb)<<12) + col*64  + (ch ^ ((col&7)<<3))
//  t2T/p2T: [pos 25][cb 32][col 64][ch 128]   elem ((pos*32+cb)<<13) + col*128 + (ch ^ ((col&7)<<3))
//  t3T/p3T: [pos 4][cb 32][col 64][ch 256]    elem ((pos*32+cb)<<14) + col*256 + (ch ^ ((col&7)<<3))
// Weights (hi/lo split bf16, fp32-equivalent):
//  W2f [25][128 oc][64 ic] (ic swz by oc&7)  — fwd2 A     (+204800 lo)
//  W2u [25][64 ic][128 oc] (oc swz by ic&7)  — upd1 A     (hi only used)
//  W3m [9][256 oc][128 ic] (ic swz by oc&7)  — fwd3 A     (+294912 lo)
//  W3u [9][128 ic][256 oc] (oc swz by ic&7)  — upd2 A     (hi only used)
// e2T/e3T: masked error tiles (same layouts as t2T/t3T), scratch in d_out.
//   Computed in fwd2m/fwd3m epilogues (bit-exact vs separate pass).
// All MFMA LDS staging uses global_load_lds width-16 (linear lane*16 dest).
// conv1s: per-ic xs restage (42KB + ws 19KB = 61KB LDS -> 2 blocks/CU);
//   FMA order per output unchanged (ic,ky,kx) -> bit-exact.
// fwd2m: 2-cb blocking. upd1m: 4-cb blocking (80KB LDS -> 2 blocks/CU,
//   grid 1568, weight stage amortized over 4 cb). fwd3m: och in [0,4).
// XCD-clustered 1-D decode (grids %8==0); upd1m cb0=(bid&7)*4 keeps the
//   same cb->XCD map as fwd3m/upd2m.
// fu3: w4s additive swizzle phys(k)=k+((k>>7)<<2), row 1056 (bank-conflict
//   fix; k0%128<=123 so paired +4 read stays in-block).
// First-iteration aliasing: t1==h1, t2==p2, t3==p3 bit-exactly.

__device__ __forceinline__ float b2f(bf16 v) { return __bfloat162float(v); }
__device__ __forceinline__ bf16  f2b(float v) { return __float2bfloat16(v); }
__device__ __forceinline__ float blo(unsigned u) { return __uint_as_float(u << 16); }
__device__ __forceinline__ float bhi(unsigned u) { return __uint_as_float(u & 0xffff0000u); }
__device__ __forceinline__ unsigned short fbits(float v) {
  union { bf16 b; unsigned short u; } c; c.b = f2b(v); return c.u;
}
__device__ __forceinline__ float ubf(unsigned short u) {
  return __uint_as_float(((unsigned)u) << 16);
}
// async global->LDS, 16B per lane. LDS dest must be wave-uniform base + lane*16.
__device__ __forceinline__ void gld16(const void* g, void* l) {
  __builtin_amdgcn_global_load_lds((const unsigned int*)g, (unsigned int*)l, 16, 0, 0);
}

// ---- weight prep ----
__global__ __launch_bounds__(256) void k_prep(
    const float* __restrict__ W1, const float* __restrict__ W2,
    const float* __restrict__ W3, float* __restrict__ W1t,
    short* __restrict__ W2f, short* __restrict__ W2u,
    short* __restrict__ W3m, short* __restrict__ W3u) {
  int i = blockIdx.x * 256 + threadIdx.x;
  if (i < 4800) {
    int oc = i / 75, k = i % 75;
    W1t[k * 64 + oc] = W1[i];
  }
  if (i < 204800) {
    int oc = i / 1600, k = i % 1600, ic = k / 25, tap = k % 25;
    float w = W2[i];
    unsigned short hi = fbits(w);
    unsigned short lo = fbits(w - ubf(hi));
    W2f[(tap * 128 + oc) * 64 + (ic ^ ((oc & 7) << 3))] = (short)hi;
    W2f[204800 + (tap * 128 + oc) * 64 + (ic ^ ((oc & 7) << 3))] = (short)lo;
    W2u[(tap * 64 + ic) * 128 + (oc ^ ((ic & 7) << 3))] = (short)hi;
  }
  if (i < 294912) {
    int oc = i / 1152, k = i % 1152, ic = k / 9, tap = k % 9;
    float w = W3[i];
    unsigned short hi = fbits(w);
    unsigned short lo = fbits(w - ubf(hi));
    W3m[(tap * 256 + oc) * 128 + (ic ^ ((oc & 7) << 3))] = (short)hi;
    W3m[294912 + (tap * 256 + oc) * 128 + (ic ^ ((oc & 7) << 3))] = (short)lo;
    W3u[(tap * 128 + ic) * 256 + (oc ^ ((ic & 7) << 3))] = (short)hi;
  }
}

// ---- conv1 (LDS-staged, 512 threads, per-ic restage): h1T = relu(conv1(x)) ----
// block=(bt,oy). LDS: xs 1-ic slab (42KB) + ws (19KB) = 61KB -> 2 blocks/CU.
// Bit-identical per-output FMA order (ic,ky,kx).
__global__ __launch_bounds__(512, 1) void k_conv1s(
    const float* __restrict__ x, const float* __restrict__ W1t,
    const float* __restrict__ b1, bf16* __restrict__ h1T) {
  __shared__ float xs[160 * 66];  // [f 160 = ky*32+x (one ic)][col 64 (+2 pad)]
  __shared__ float ws[4800];      // [tap 75][oc 64]
  int bt = blockIdx.x, oy = blockIdx.y;
  int tid = threadIdx.x, lane = tid & 63, w8 = tid >> 6;
  int wv = w8 & 3, h = w8 >> 2;
  for (int i = tid; i < 4800; i += 512) ws[i] = W1t[i];
  int oc0 = wv * 16;
  float acc[7][16];
#pragma unroll
  for (int o = 0; o < 7; ++o)
#pragma unroll
    for (int j = 0; j < 16; ++j) acc[o][j] = b1[oc0 + j];
  for (int ic = 0; ic < 3; ++ic) {
    __syncthreads();  // prior compute done (and ws visible on first pass)
    // x slab for this ic: 2560 float4 = 64 col x 40 chunks (640B runs)
#pragma unroll
    for (int r = 0; r < 5; ++r) {
      int idx = r * 512 + tid;
      int col = idx / 40, rem = idx % 40;
      float4 v = *(const float4*)(x + (size_t)(bt * 64 + col) * 3072 +
                                  ic * 1024 + oy * 64 + rem * 4);
      float* d = xs + (rem * 4) * 66 + col;
      d[0] = v.x;
      d[66] = v.y;
      d[132] = v.z;
      d[198] = v.w;
    }
    __syncthreads();
    for (int ky = 0; ky < 5; ++ky) {
#pragma unroll
      for (int kx = 0; kx < 5; ++kx) {
        const float* wp = ws + ((ic * 25 + ky * 5 + kx) << 6) + oc0;
        float4 w0 = *(const float4*)(wp);
        float4 w1 = *(const float4*)(wp + 4);
        float4 w2 = *(const float4*)(wp + 8);
        float4 w3 = *(const float4*)(wp + 12);
        const float* xr = xs + (ky * 32 + kx) * 66 + lane;
        float xv[7];
#pragma unroll
        for (int o = 0; o < 7; ++o) xv[o] = xr[(2 * (h * 7 + o)) * 66];
#pragma unroll
        for (int o = 0; o < 7; ++o) {
          float e = xv[o];
          acc[o][0] += e * w0.x;  acc[o][1] += e * w0.y;
          acc[o][2] += e * w0.z;  acc[o][3] += e * w0.w;
          acc[o][4] += e * w1.x;  acc[o][5] += e * w1.y;
          acc[o][6] += e * w1.z;  acc[o][7] += e * w1.w;
          acc[o][8] += e * w2.x;  acc[o][9] += e * w2.y;
          acc[o][10] += e * w2.z; acc[o][11] += e * w2.w;
          acc[o][12] += e * w3.x; acc[o][13] += e * w3.y;
          acc[o][14] += e * w3.z; acc[o][15] += e * w3.w;
        }
      }
    }
  }
#pragma unroll
  for (int o = 0; o < 7; ++o) {
    int pix = oy * 14 + h * 7 + o;
    size_t tbase = ((size_t)(pix * 32 + bt)) << 12;
#pragma unroll
    for (int q = 0; q < 4; ++q) {
      ushort4 pk;
      pk.x = fbits(fmaxf(acc[o][q * 4 + 0], 0.f));
      pk.y = fbits(fmaxf(acc[o][q * 4 + 1], 0.f));
      pk.z = fbits(fmaxf(acc[o][q * 4 + 2], 0.f));
      pk.w = fbits(fmaxf(acc[o][q * 4 + 3], 0.f));
      int ocr = oc0 + q * 4;
      size_t off = tbase + lane * 64 + (ocr ^ ((lane & 7) << 3));
      *(ushort4*)(h1T + off) = pk;
    }
  }
}

// ---- fwd2 (MFMA, 2-cb): p2T = relu(conv2(in1)); fused e2T ----
// grid 400 (1-D): xcd=bid&7, j=bid>>3 (0..49), cbp=xcd*2+(j&1), pos=j>>1
__global__ __launch_bounds__(256) void k_fwd2m(
    const bf16* __restrict__ in1, const short* __restrict__ W2f,
    const float* __restrict__ b2, bf16* __restrict__ p2T,
    const bf16* __restrict__ t2e, bf16* __restrict__ e2T, int einit) {
  __shared__ __align__(16) short As0[8192];     // hi [128 oc][64 ic]
  __shared__ __align__(16) short As1[8192];     // lo
  __shared__ __align__(16) short Bs[2][4096];   // [cb][64 col][64 ic]
  int bid = blockIdx.x;
  int j = bid >> 3;
  int cbp = (bid & 7) * 2 + (j & 1), pos = j >> 1;
  int cb0 = cbp * 2;
  int tid = threadIdx.x, lane = tid & 63, wv = tid >> 6;
  int oy = pos / 5, ox = pos % 5;
  float4v acc[2][2][4];
#pragma unroll
  for (int c = 0; c < 2; ++c)
#pragma unroll
    for (int m = 0; m < 2; ++m)
#pragma unroll
      for (int n = 0; n < 4; ++n) acc[c][m][n] = (float4v){0.f, 0.f, 0.f, 0.f};

  for (int tap = 0; tap < 25; ++tap) {
    int ky = tap / 5, kx = tap % 5;
    int ipix = (2 * oy + ky) * 14 + (2 * ox + kx);
    __syncthreads();
    {
      const uint4* bs0 = (const uint4*)(in1 + (((size_t)(ipix * 32 + cb0)) << 12));
      const uint4* bs1 = (const uint4*)(in1 + (((size_t)(ipix * 32 + cb0 + 1)) << 12));
      uint4* bd = (uint4*)Bs;
      gld16(&bs0[tid], &bd[tid]);
      gld16(&bs0[tid + 256], &bd[tid + 256]);
      gld16(&bs1[tid], &bd[tid + 512]);
      gld16(&bs1[tid + 256], &bd[tid + 768]);
      const uint4* ah = (const uint4*)(W2f + tap * 8192);
      const uint4* al = (const uint4*)(W2f + 204800 + tap * 8192);
      uint4* dh = (uint4*)As0;
      uint4* dl = (uint4*)As1;
#pragma unroll
      for (int p = 0; p < 4; ++p) {
        gld16(&ah[tid + p * 256], &dh[tid + p * 256]);
        gld16(&al[tid + p * 256], &dl[tid + p * 256]);
      }
    }
    __syncthreads();
#pragma unroll
    for (int ks = 0; ks < 2; ++ks) {
      int ic0 = ks * 32 + ((lane >> 4) << 3);
      short8v bfr[2][4];
#pragma unroll
      for (int c = 0; c < 2; ++c)
#pragma unroll
        for (int n = 0; n < 4; ++n) {
          int colv = n * 16 + (lane & 15);
          bfr[c][n] = *(const short8v*)(&Bs[c][0] + colv * 64 + (ic0 ^ ((colv & 7) << 3)));
        }
#pragma unroll
      for (int m = 0; m < 2; ++m) {
        int row = wv * 32 + m * 16 + (lane & 15);
        int aoff = row * 64 + (ic0 ^ ((row & 7) << 3));
        short8v ah = *(const short8v*)(As0 + aoff);
        short8v al = *(const short8v*)(As1 + aoff);
#pragma unroll
        for (int c = 0; c < 2; ++c)
#pragma unroll
          for (int n = 0; n < 4; ++n) {
            acc[c][m][n] = __builtin_amdgcn_mfma_f32_16x16x32_bf16(ah, bfr[c][n], acc[c][m][n], 0, 0, 0);
            acc[c][m][n] = __builtin_amdgcn_mfma_f32_16x16x32_bf16(al, bfr[c][n], acc[c][m][n], 0, 0, 0);
          }
      }
    }
  }
#pragma unroll
  for (int c = 0; c < 2; ++c) {
    size_t tb2 = ((size_t)(pos * 32 + cb0 + c)) << 13;
#pragma unroll
    for (int m = 0; m < 2; ++m) {
      int ocb = wv * 32 + m * 16 + ((lane >> 4) << 2);
      float4 bv = *(const float4*)(b2 + ocb);
#pragma unroll
      for (int n = 0; n < 4; ++n) {
        int colv = n * 16 + (lane & 15);
        ushort4 pk;
        pk.x = fbits(fmaxf(acc[c][m][n][0] + bv.x, 0.f));
        pk.y = fbits(fmaxf(acc[c][m][n][1] + bv.y, 0.f));
        pk.z = fbits(fmaxf(acc[c][m][n][2] + bv.z, 0.f));
        pk.w = fbits(fmaxf(acc[c][m][n][3] + bv.w, 0.f));
        size_t off = tb2 + colv * 128 + (ocb ^ ((colv & 7) << 3));
        *(ushort4*)(p2T + off) = pk;
        if (einit) {
          ushort4 z = {0, 0, 0, 0};
          *(ushort4*)(e2T + off) = z;
        } else {
          ushort4 tv = *(const ushort4*)(t2e + off);
          ushort4 ev;
          float p0, t0;
          p0 = ubf(pk.x); t0 = ubf(tv.x); ev.x = fbits(p0 > 0.f ? t0 - p0 : 0.f);
          p0 = ubf(pk.y); t0 = ubf(tv.y); ev.y = fbits(p0 > 0.f ? t0 - p0 : 0.f);
          p0 = ubf(pk.z); t0 = ubf(tv.z); ev.z = fbits(p0 > 0.f ? t0 - p0 : 0.f);
          p0 = ubf(pk.w); t0 = ubf(tv.w); ev.w = fbits(p0 > 0.f ? t0 - p0 : 0.f);
          *(ushort4*)(e2T + off) = ev;
        }
      }
    }
  }
}

// ---- upd1 (MFMA, hi-only, 4-cb): g1 = conv2^T(e2T); t1w = upd(t1r) ----
// grid 1568 (1-D): xcd=bid&7, pix=bid>>3 (0..195), cb0=xcd*4
// LDS 80KB -> 2 blocks/CU; weight stage amortized over 4 cb.
__global__ __launch_bounds__(256) void k_upd1m(
    const bf16* __restrict__ e2T, const short* __restrict__ W2u,
    const bf16* __restrict__ h1T, const bf16* __restrict__ t1r,
    bf16* __restrict__ t1w) {
  __shared__ __align__(16) short As0[8192];    // hi [64 ic][128 oc]
  __shared__ __align__(16) short Es[4][8192];  // [cb][64 col][128 oc]
  int bid = blockIdx.x;
  int pix = bid >> 3;
  int cb0 = (bid & 7) * 4;
  int tid = threadIdx.x, lane = tid & 63, wv = tid >> 6;
  int iy = pix / 14, ix = pix % 14;
  float4v acc[4][4];
#pragma unroll
  for (int c = 0; c < 4; ++c)
#pragma unroll
    for (int n = 0; n < 4; ++n) acc[c][n] = (float4v){0.f, 0.f, 0.f, 0.f};

  for (int ky = iy & 1; ky <= 4; ky += 2) {
    int oy = (iy - ky) >> 1;
    if (oy < 0 || oy > 4) continue;
    for (int kx = ix & 1; kx <= 4; kx += 2) {
      int ox = (ix - kx) >> 1;
      if (ox < 0 || ox > 4) continue;
      int erow = oy * 5 + ox, tap = ky * 5 + kx;
      __syncthreads();
      {
        const uint4* es0 = (const uint4*)(e2T + (((size_t)(erow * 32 + cb0)) << 13));
        const uint4* es1 = (const uint4*)(e2T + (((size_t)(erow * 32 + cb0 + 1)) << 13));
        const uint4* es2 = (const uint4*)(e2T + (((size_t)(erow * 32 + cb0 + 2)) << 13));
        const uint4* es3 = (const uint4*)(e2T + (((size_t)(erow * 32 + cb0 + 3)) << 13));
        uint4* ed = (uint4*)Es;
        const uint4* ah = (const uint4*)(W2u + tap * 8192);
        uint4* dh = (uint4*)As0;
#pragma unroll
        for (int p = 0; p < 4; ++p) {
          gld16(&es0[tid + p * 256], &ed[tid + p * 256]);
          gld16(&es1[tid + p * 256], &ed[tid + p * 256 + 1024]);
          gld16(&es2[tid + p * 256], &ed[tid + p * 256 + 2048]);
          gld16(&es3[tid + p * 256], &ed[tid + p * 256 + 3072]);
          gld16(&ah[tid + p * 256], &dh[tid + p * 256]);
        }
      }
      __syncthreads();
#pragma unroll
      for (int ks = 0; ks < 4; ++ks) {
        int oc0 = ks * 32 + ((lane >> 4) << 3);
        int row = wv * 16 + (lane & 15);
        int aoff = row * 128 + (oc0 ^ ((row & 7) << 3));
        short8v ah = *(const short8v*)(As0 + aoff);
#pragma unroll
        for (int c = 0; c < 4; ++c)
#pragma unroll
          for (int n = 0; n < 4; ++n) {
            int colv = n * 16 + (lane & 15);
            short8v ef = *(const short8v*)(&Es[c][0] + colv * 128 + (oc0 ^ ((colv & 7) << 3)));
            acc[c][n] = __builtin_amdgcn_mfma_f32_16x16x32_bf16(ah, ef, acc[c][n], 0, 0, 0);
          }
      }
    }
  }
  int icb = wv * 16 + ((lane >> 4) << 2);
#pragma unroll
  for (int c = 0; c < 4; ++c) {
    size_t tb1 = ((size_t)(pix * 32 + cb0 + c)) << 12;
#pragma unroll
    for (int n = 0; n < 4; ++n) {
      int colv = n * 16 + (lane & 15);
      size_t off = tb1 + colv * 64 + (icb ^ ((colv & 7) << 3));
      ushort4 tv = *(const ushort4*)(t1r + off);
      ushort4 hv = *(const ushort4*)(h1T + off);
      ushort4 rp;
      float t0, h0;
      t0 = ubf(tv.x); h0 = ubf(hv.x);
      rp.x = fbits(t0 - 0.07f * (t0 - h0) + 0.07f * acc[c][n][0]);
      t0 = ubf(tv.y); h0 = ubf(hv.y);
      rp.y = fbits(t0 - 0.07f * (t0 - h0) + 0.07f * acc[c][n][1]);
      t0 = ubf(tv.z); h0 = ubf(hv.z);
      rp.z = fbits(t0 - 0.07f * (t0 - h0) + 0.07f * acc[c][n][2]);
      t0 = ubf(tv.w); h0 = ubf(hv.w);
      rp.w = fbits(t0 - 0.07f * (t0 - h0) + 0.07f * acc[c][n][3]);
      *(ushort4*)(t1w + off) = rp;
    }
  }
}

// ---- fwd3 (MFMA): p3T = relu(conv3(in2)); fused e3T = mask(p3)*(t3e-p3) ----
// grid 512 (1-D): xcd=bid&7, j=bid>>3, cb=xcd*4+(j&3), r=j>>2, pos=r&3, och=r>>2
__global__ __launch_bounds__(256) void k_fwd3m(
    const bf16* __restrict__ in2, const short* __restrict__ W3m,
    const float* __restrict__ b3, bf16* __restrict__ p3T,
    const bf16* __restrict__ t3e, bf16* __restrict__ e3T, int einit) {
  __shared__ __align__(16) short As0[8192];  // hi [64 oc][128 ic]
  __shared__ __align__(16) short As1[8192];  // lo
  __shared__ __align__(16) short Bs[8192];   // [64 col][128 ic]
  int bid = blockIdx.x;
  int j = bid >> 3;
  int cb = (bid & 7) * 4 + (j & 3);
  int r = j >> 2;
  int pos = r & 3, och = r >> 2;
  int tid = threadIdx.x, lane = tid & 63, wv = tid >> 6;
  int oy = pos >> 1, ox = pos & 1;
  float4v acc[4];
#pragma unroll
  for (int n = 0; n < 4; ++n) acc[n] = (float4v){0.f, 0.f, 0.f, 0.f};

  for (int tap = 0; tap < 9; ++tap) {
    int ky = tap / 3, kx = tap % 3;
    int irow = (2 * oy + ky) * 5 + (2 * ox + kx);
    __syncthreads();
    {
      const uint4* bs = (const uint4*)(in2 + (((size_t)(irow * 32 + cb)) << 13));
      uint4* bd = (uint4*)Bs;
#pragma unroll
      for (int p = 0; p < 4; ++p) gld16(&bs[tid + p * 256], &bd[tid + p * 256]);
      const uint4* ah = (const uint4*)(W3m + ((size_t)tap * 256 + och * 64) * 128);
      const uint4* al = (const uint4*)(W3m + 294912 + ((size_t)tap * 256 + och * 64) * 128);
      uint4* dh = (uint4*)As0;
      uint4* dl = (uint4*)As1;
#pragma unroll
      for (int p = 0; p < 4; ++p) {
        gld16(&ah[tid + p * 256], &dh[tid + p * 256]);
        gld16(&al[tid + p * 256], &dl[tid + p * 256]);
      }
    }
    __syncthreads();
#pragma unroll
    for (int ks = 0; ks < 4; ++ks) {
      int ic0 = ks * 32 + ((lane >> 4) << 3);
      short8v bfr[4];
#pragma unroll
      for (int n = 0; n < 4; ++n) {
        int colv = n * 16 + (lane & 15);
        bfr[n] = *(const short8v*)(Bs + colv * 128 + (ic0 ^ ((colv & 7) << 3)));
      }
      int row = wv * 16 + (lane & 15);
      int aoff = row * 128 + (ic0 ^ ((row & 7) << 3));
      short8v ah = *(const short8v*)(As0 + aoff);
      short8v al = *(const short8v*)(As1 + aoff);
#pragma unroll
      for (int n = 0; n < 4; ++n) {
        acc[n] = __builtin_amdgcn_mfma_f32_16x16x32_bf16(ah, bfr[n], acc[n], 0, 0, 0);
        acc[n] = __builtin_amdgcn_mfma_f32_16x16x32_bf16(al, bfr[n], acc[n], 0, 0, 0);
      }
    }
  }
  size_t tb3 = ((size_t)(pos * 32 + cb)) << 14;
  int ocg = och * 64 + wv * 16 + ((lane >> 4) << 2);
  float4 bv = *(const float4*)(b3 + ocg);
#pragma unroll
  for (int n = 0; n < 4; ++n) {
    int colv = n * 16 + (lane & 15);
    ushort4 pk;
    pk.x = fbits(fmaxf(acc[n][0] + bv.x, 0.f));
    pk.y = fbits(fmaxf(acc[n][1] + bv.y, 0.f));
    pk.z = fbits(fmaxf(acc[n][2] + bv.z, 0.f));
    pk.w = fbits(fmaxf(acc[n][3] + bv.w, 0.f));
    size_t off = tb3 + colv * 256 + (ocg ^ ((colv & 7) << 3));
    *(ushort4*)(p3T + off) = pk;
    if (einit) {
      ushort4 z = {0, 0, 0, 0};
      *(ushort4*)(e3T + off) = z;
    } else {
      ushort4 tv = *(const ushort4*)(t3e + off);
      ushort4 ev;
      float p0, t0;
      p0 = ubf(pk.x); t0 = ubf(tv.x); ev.x = fbits(p0 > 0.f ? t0 - p0 : 0.f);
      p0 = ubf(pk.y); t0 = ubf(tv.y); ev.y = fbits(p0 > 0.f ? t0 - p0 : 0.f);
      p0 = ubf(pk.z); t0 = ubf(tv.z); ev.z = fbits(p0 > 0.f ? t0 - p0 : 0.f);
      p0 = ubf(pk.w); t0 = ubf(tv.w); ev.w = fbits(p0 > 0.f ? t0 - p0 : 0.f);
      *(ushort4*)(e3T + off) = ev;
    }
  }
}

// ---- upd2 (MFMA, hi-only): g2 = conv3^T(e3T); t2w = upd(t2r) ----
// grid 800 (1-D): xcd=bid&7, j=bid>>3, cb=xcd*4+(j&3), pix=j>>2
__global__ __launch_bounds__(256) void k_upd2m(
    const bf16* __restrict__ e3T, const bf16* __restrict__ p2T,
    const short* __restrict__ W3u, const bf16* __restrict__ t2r,
    bf16* __restrict__ t2w) {
  __shared__ __align__(16) short Es[8192];    // [64 col][128 oc_local]
  __shared__ __align__(16) short As0[16384];  // hi [128 ic][128 oc_local]
  int bid = blockIdx.x;
  int j = bid >> 3;
  int cb = (bid & 7) * 4 + (j & 3), pix = j >> 2;
  int tid = threadIdx.x, lane = tid & 63, wv = tid >> 6;
  int iy = pix / 5, ix = pix % 5;
  float4v acc[2][4];
#pragma unroll
  for (int m = 0; m < 2; ++m)
#pragma unroll
    for (int n = 0; n < 4; ++n) acc[m][n] = (float4v){0.f, 0.f, 0.f, 0.f};

  for (int ky = iy & 1; ky <= 2; ky += 2) {
    int oy = (iy - ky) >> 1;
    if (oy < 0 || oy > 1) continue;
    for (int kx = ix & 1; kx <= 2; kx += 2) {
      int ox = (ix - kx) >> 1;
      if (ox < 0 || ox > 1) continue;
      int erow = oy * 2 + ox, tap = ky * 3 + kx;
      for (int occ = 0; occ < 2; ++occ) {
        __syncthreads();
        {
          size_t tb = ((size_t)(erow * 32 + cb)) << 14;
          uint4* ed = (uint4*)Es;
#pragma unroll
          for (int p = 0; p < 4; ++p) {
            int fi = tid + p * 256;
            int colr = fi >> 4, q = fi & 15;
            size_t g = tb + colr * 256 + occ * 128 + q * 8;
            gld16(e3T + g, &ed[fi]);
          }
          uint4* dh = (uint4*)As0;
#pragma unroll
          for (int p = 0; p < 8; ++p) {
            int fi = tid + p * 256;
            int icr = fi >> 4, q = fi & 15;
            size_t srcoff = ((size_t)(tap * 128 + icr)) * 256 + occ * 128 + q * 8;
            gld16(W3u + srcoff, &dh[fi]);
          }
        }
        __syncthreads();
#pragma unroll
        for (int ks = 0; ks < 4; ++ks) {
          int oc0 = ks * 32 + ((lane >> 4) << 3);
          short8v efr[4];
#pragma unroll
          for (int n = 0; n < 4; ++n) {
            int colv = n * 16 + (lane & 15);
            efr[n] = *(const short8v*)(Es + colv * 128 + (oc0 ^ ((colv & 7) << 3)));
          }
#pragma unroll
          for (int m = 0; m < 2; ++m) {
            int icr = wv * 32 + m * 16 + (lane & 15);
            int aoff = icr * 128 + (oc0 ^ ((icr & 7) << 3));
            short8v ah = *(const short8v*)(As0 + aoff);
#pragma unroll
            for (int n = 0; n < 4; ++n) {
              acc[m][n] = __builtin_amdgcn_mfma_f32_16x16x32_bf16(ah, efr[n], acc[m][n], 0, 0, 0);
            }
          }
        }
      }
    }
  }
  size_t tb2 = ((size_t)(pix * 32 + cb)) << 13;
#pragma unroll
  for (int m = 0; m < 2; ++m) {
    int icr = wv * 32 + m * 16 + ((lane >> 4) << 2);
#pragma unroll
    for (int n = 0; n < 4; ++n) {
      int colv = n * 16 + (lane & 15);
      size_t off = tb2 + colv * 128 + (icr ^ ((colv & 7) << 3));
      ushort4 tv = *(const ushort4*)(t2r + off);
      ushort4 pv = *(const ushort4*)(p2T + off);
      ushort4 rp;
      float t0, p0;
      t0 = ubf(tv.x); p0 = ubf(pv.x);
      rp.x = fbits(t0 - 0.07f * (t0 - p0) + 0.07f * acc[m][n][0]);
      t0 = ubf(tv.y); p0 = ubf(pv.y);
      rp.y = fbits(t0 - 0.07f * (t0 - p0) + 0.07f * acc[m][n][1]);
      t0 = ubf(tv.z); p0 = ubf(pv.z);
      rp.z = fbits(t0 - 0.07f * (t0 - p0) + 0.07f * acc[m][n][2]);
      t0 = ubf(tv.w); p0 = ubf(pv.w);
      rp.w = fbits(t0 - 0.07f * (t0 - p0) + 0.07f * acc[m][n][3]);
      *(ushort4*)(t2w + off) = rp;
    }
  }
}

// ---- fu3: p4 = t3r @ W4^T + b4 (all-lane butterfly); softmax; e4;
//      g3 = e4 @ W4; t3w = upd(t3r).
//      w4s bank-conflict-free: phys(k) = k + ((k>>7)<<2), row stride 1056. ----
__global__ __launch_bounds__(256) void k_fu3(
    const float* __restrict__ gt, const float* __restrict__ W4,
    const float* __restrict__ b4, const bf16* __restrict__ p3T,
    const bf16* __restrict__ t3r, bf16* __restrict__ t3w) {
  __shared__ __align__(16) float w4s[10560];  // 10 rows x 1056 (swizzled)
  int tid = threadIdx.x;
  for (int i = tid; i < 10240; i += 256) {
    int o = i >> 10, k = i & 1023;
    w4s[o * 1056 + k + ((k >> 7) << 2)] = W4[i];
  }
  __syncthreads();
  int c = blockIdx.x * 8 + (tid >> 5);
  int cb = c >> 6, colL = c & 63, subk = tid & 31;
  int pos = subk & 3, ch0 = (subk >> 2) * 32;
  int xc = (colL & 7) << 3;
  size_t boff = (((size_t)(pos * 32 + cb)) << 14) + colL * 256 + ch0;
  const bf16* trd = t3r + boff;
  const bf16* pb = p3T + boff;
  uint4 tq[4];
#pragma unroll
  for (int q = 0; q < 4; ++q) tq[q] = *(const uint4*)(trd + q * 8);
  float acc[10] = {};
#pragma unroll
  for (int q = 0; q < 4; ++q) {
    unsigned wds[4] = {tq[q].x, tq[q].y, tq[q].z, tq[q].w};
    int chb = (ch0 + q * 8) ^ xc;
#pragma unroll
    for (int h = 0; h < 4; ++h) {
      float v0 = blo(wds[h]), v1 = bhi(wds[h]);
      int k0 = (chb + 2 * h) * 4 + pos;
      int ks = k0 + ((k0 >> 7) << 2);  // k0%128<=123 so +4 stays in-block
#pragma unroll
      for (int o = 0; o < 10; ++o)
        acc[o] += v0 * w4s[o * 1056 + ks] + v1 * w4s[o * 1056 + ks + 4];
    }
  }
#pragma unroll
  for (int off = 16; off > 0; off >>= 1)
#pragma unroll
    for (int o = 0; o < 10; ++o) acc[o] += __shfl_xor(acc[o], off, 32);
  float pv[10], m = -1e30f;
#pragma unroll
  for (int o = 0; o < 10; ++o) {
    pv[o] = acc[o] + b4[o];
    m = fmaxf(m, pv[o]);
  }
  float s = 0.f;
#pragma unroll
  for (int o = 0; o < 10; ++o) {
    pv[o] = __expf(pv[o] - m);
    s += pv[o];
  }
  float inv = 1.f / s;
  float e4[10];
#pragma unroll
  for (int o = 0; o < 10; ++o)
    e4[o] = (gt[(size_t)c * 10 + o] - pv[o] * inv) * 0.5f;
  bf16* tb = t3w + boff;
#pragma unroll
  for (int q = 0; q < 4; ++q) {
    uint4 pq = *(const uint4*)(pb + q * 8);
    unsigned tw[4] = {tq[q].x, tq[q].y, tq[q].z, tq[q].w};
    unsigned pw[4] = {pq.x, pq.y, pq.z, pq.w};
    int chb = (ch0 + q * 8) ^ xc;
    unsigned ro[4];
#pragma unroll
    for (int h = 0; h < 4; ++h) {
      int k0 = (chb + 2 * h) * 4 + pos;
      int ks = k0 + ((k0 >> 7) << 2);
      float g0 = 0.f, g1 = 0.f;
#pragma unroll
      for (int o = 0; o < 10; ++o) {
        g0 += e4[o] * w4s[o * 1056 + ks];
        g1 += e4[o] * w4s[o * 1056 + ks + 4];
      }
      float t0 = blo(tw[h]), p0 = blo(pw[h]);
      float t1 = bhi(tw[h]), p1 = bhi(pw[h]);
      float r0 = t0 - 0.07f * (t0 - p0) + 0.07f * g0;
      float r1 = t1 - 0.07f * (t1 - p1) + 0.07f * g1;
      ro[h] = (unsigned)fbits(r0) | ((unsigned)fbits(r1) << 16);
    }
    uint4 rv = {ro[0], ro[1], ro[2], ro[3]};
    *(uint4*)(tb + q * 8) = rv;
  }
}

// ---- k_tr1: t1 section gather (contiguous slab reads, LDS rotate) ----
__global__ __launch_bounds__(256) void k_tr1(
    const bf16* __restrict__ t1T, float* __restrict__ out) {
  __shared__ short lds[2 * 64 * 224];
  int cb = blockIdx.x, c0 = blockIdx.y * 2;
  int tid = threadIdx.x;
  for (int i = tid; i < 3136; i += 256) {
    int pix = i >> 4, q = i & 15;
    int colL = q >> 3, chb = (q & 7) << 3;
    int col = c0 + colL;
    uint4 v = *(const uint4*)(t1T + (((size_t)(pix * 32 + cb)) << 12) + col * 64 + chb);
    int icb = chb ^ ((col & 7) << 3);
    int posX = pix ^ (((icb >> 3) & 7) << 2);
    short* d = lds + (colL * 64 + icb) * 224 + posX;
    const short* vs = (const short*)&v;
#pragma unroll
    for (int j = 0; j < 8; ++j) d[j * 224] = vs[j];
  }
  __syncthreads();
  for (int i = tid; i < 6272; i += 256) {
    int colL = i / 3136, m = i % 3136;
    int ic = m / 49, pp = m % 49;
    int posX = (pp * 4) ^ (((ic >> 3) & 7) << 2);
    const short* s = lds + (colL * 64 + ic) * 224 + posX;
    float4 o;
    o.x = ubf((unsigned short)s[0]);
    o.y = ubf((unsigned short)s[1]);
    o.z = ubf((unsigned short)s[2]);
    o.w = ubf((unsigned short)s[3]);
    *(float4*)(out + ((size_t)(cb * 64 + c0 + colL)) * 16768 + m * 4) = o;
  }
}

// ---- k_tr2: t2 section gather ----
__global__ __launch_bounds__(256) void k_tr2(
    const bf16* __restrict__ t2T, float* __restrict__ out) {
  __shared__ short lds[4 * 128 * 32];
  int cb = blockIdx.x, c0 = blockIdx.y * 4;
  int tid = threadIdx.x;
  for (int i = tid; i < 1600; i += 256) {
    int pos = i >> 6, q = i & 63;
    int colL = q >> 4, chb = (q & 15) << 3;
    int col = c0 + colL;
    uint4 v = *(const uint4*)(t2T + (((size_t)(pos * 32 + cb)) << 13) + col * 128 + chb);
    int ocb = chb ^ ((col & 7) << 3);
    int posX = pos ^ (((ocb >> 3) & 7) << 2);
    short* d = lds + (colL * 128 + ocb) * 32 + posX;
    const short* vs = (const short*)&v;
#pragma unroll
    for (int j = 0; j < 8; ++j) d[j * 32] = vs[j];
  }
  __syncthreads();
  for (int i = tid; i < 3200; i += 256) {
    int colL = i / 800, m = i % 800;
    int f0 = m * 4;
    float4 o;
    float* po = &o.x;
#pragma unroll
    for (int t = 0; t < 4; ++t) {
      int f = f0 + t;
      int oc = f / 25, pos = f % 25;
      int posX = pos ^ (((oc >> 3) & 7) << 2);
      po[t] = ubf((unsigned short)lds[(colL * 128 + oc) * 32 + posX]);
    }
    *(float4*)(out + ((size_t)(cb * 64 + c0 + colL)) * 16768 + 12544 + f0) = o;
  }
}

// ---- k_tr3: t3 section gather, register transpose ----
__global__ __launch_bounds__(256) void k_tr3(
    const bf16* __restrict__ t3T, float* __restrict__ out) {
  int tid = threadIdx.x;
  int sample = blockIdx.x * 8 + (tid >> 5);
  int cb = sample >> 6, col = sample & 63;
  int chb = (tid & 31) << 3;
  int icb = chb ^ ((col & 7) << 3);
  uint4 v[4];
#pragma unroll
  for (int pos = 0; pos < 4; ++pos)
    v[pos] = *(const uint4*)(t3T + (((size_t)(pos * 32 + cb)) << 14) + col * 256 + chb);
  const unsigned short* s0 = (const unsigned short*)&v[0];
  const unsigned short* s1 = (const unsigned short*)&v[1];
  const unsigned short* s2 = (const unsigned short*)&v[2];
  const unsigned short* s3 = (const unsigned short*)&v[3];
  float* ob = out + (size_t)sample * 16768 + 15744 + icb * 4;
#pragma unroll
  for (int j = 0; j < 8; ++j) {
    float4 o;
    o.x = ubf(s0[j]);
    o.y = ubf(s1[j]);
    o.z = ubf(s2[j]);
    o.w = ubf(s3[j]);
    *(float4*)(ob + j * 4) = o;
  }
}

extern "C" void kernel_launch(void* const* d_in, const int* in_sizes, int n_in,
                              void* d_out, int out_size, void* d_ws,
                              size_t ws_size, hipStream_t stream) {
  const float* x  = (const float*)d_in[0];
  const float* gt = (const float*)d_in[1];
  const float* W1 = (const float*)d_in[2];
  const float* b1 = (const float*)d_in[3];
  const float* W2 = (const float*)d_in[4];
  const float* b2 = (const float*)d_in[5];
  const float* W3 = (const float*)d_in[6];
  const float* b3 = (const float*)d_in[7];
  const float* W4 = (const float*)d_in[8];
  const float* b4 = (const float*)d_in[9];
  float* out = (float*)d_out;

  bf16* h1T = (bf16*)d_ws;
  bf16* t1T = h1T + 25690112ull;
  bf16* t2T = t1T + 25690112ull;
  bf16* p2T = t2T + 6553600ull;
  bf16* t3T = p2T + 6553600ull;
  bf16* p3T = t3T + 2097152ull;
  float* p4f = (float*)(p3T + 2097152ull);  // unused (kept for layout)
  float* W1t = p4f + 20480;
  short* W3m = (short*)(W1t + 4800);
  short* W3u = W3m + 589824;
  short* W2f = W3u + 589824;
  short* W2u = W2f + 409600;
  // e2T/e3T (13.1 + 4.2 MB bf16) live in d_out (134 MB), dead until k_tr*.
  bf16* e2T = (bf16*)out;
  bf16* e3T = e2T + 6553600ull;

  dim3 blk(256);

  k_prep<<<1152, blk, 0, stream>>>(W1, W2, W3, W1t, W2f, W2u, W3m, W3u);
  k_conv1s<<<dim3(32, 14), dim3(512), 0, stream>>>(x, W1t, b1, h1T);
  k_fwd2m<<<400, blk, 0, stream>>>(h1T, W2f, b2, p2T, p2T, e2T, 1);
  k_fwd3m<<<512, blk, 0, stream>>>(p2T, W3m, b3, p3T, p3T, e3T, 1);

  for (int it = 0; it < 25; ++it) {
    const bf16* t1r = (it == 0) ? h1T : t1T;
    const bf16* t2r = (it == 0) ? p2T : t2T;
    const bf16* t3r = (it == 0) ? p3T : t3T;
    k_upd1m<<<1568, blk, 0, stream>>>(e2T, W2u, h1T, t1r, t1T);
    k_upd2m<<<800, blk, 0, stream>>>(e3T, p2T, W3u, t2r, t2T);
    k_fu3<<<256, blk, 0, stream>>>(gt, W4, b4, p3T, t3r, t3T);
    if (it < 24) {
      k_fwd2m<<<400, blk, 0, stream>>>(t1T, W2f, b2, p2T, t2T, e2T, 0);
      k_fwd3m<<<512, blk, 0, stream>>>(t2T, W3m, b3, p3T, t3T, e3T, 0);
    }
  }
  k_tr1<<<dim3(32, 32), blk, 0, stream>>>(t1T, out);
  k_tr2<<<dim3(32, 16), blk, 0, stream>>>(t2T, out);
  k_tr3<<<256, blk, 0, stream>>>(t3T, out);
}

// Round 13
// 3425.020 us; speedup vs baseline: 1.0256x; 1.0256x over previous
//
#include <hip/hip_runtime.h>
#include <hip/hip_bf16.h>

typedef __hip_bfloat16 bf16;
typedef __attribute__((ext_vector_type(8))) short short8v;   // 8 bf16 (4 VGPR)
typedef __attribute__((ext_vector_type(4))) float float4v;   // MFMA acc

// ---------------- layouts ----------------
// Tile layouts (bf16, XOR-swizzled channel dim, batch=2048 in 32 blocks of 64):
//  t1T/h1T: [pix 196][cb 32][col 64][ch 64]   elem ((pix*32+cb)<<12) + col*64  + (ch ^ ((col&7)<<3))
//  t2T/p2T: [pos 25][cb 32][col 64][ch 128]   elem ((pos*32+cb)<<13) + col*128 + (ch ^ ((col&7)<<3))
//  t3T/p3T: [pos 4][cb 32][col 64][ch 256]    elem ((pos*32+cb)<<14) + col*256 + (ch ^ ((col&7)<<3))
// Weights (hi/lo split bf16, fp32-equivalent):
//  W2f [25][128 oc][64 ic] (ic swz by oc&7)  — fwd2 A     (+204800 lo)
//  W2u [25][64 ic][128 oc] (oc swz by ic&7)  — upd1 A     (hi only used)
//  W3m [9][256 oc][128 ic] (ic swz by oc&7)  — fwd3 A     (+294912 lo)
//  W3u [9][128 ic][256 oc] (oc swz by ic&7)  — upd2 A     (hi only used)
// e2T/e3T: masked error tiles (same layouts as t2T/t3T), scratch in d_out.
//   Computed in fwd2m/fwd3m epilogues (bit-exact vs separate pass).
// All MFMA LDS staging uses global_load_lds width-16 (linear lane*16 dest).
// Operating point for loop MFMA kernels: 48KB LDS -> 3 blocks/CU (proven;
//   dropping below it regressed twice). fwd2m/upd1m/upd2m: 2-cb blocking
//   (shared weight stage). fwd3m: och in [0,4) (64 oc rows/block).
// XCD-clustered 1-D decode (grids %8==0): cb clusters of 4 per XCD.
// fu3: w4s additive swizzle phys(k)=k+((k>>7)<<2), row 1056 (bank-conflict
//   fix; k0%128<=123 so paired +4 read stays in-block).
// First-iteration aliasing: t1==h1, t2==p2, t3==p3 bit-exactly.

__device__ __forceinline__ float b2f(bf16 v) { return __bfloat162float(v); }
__device__ __forceinline__ bf16  f2b(float v) { return __float2bfloat16(v); }
__device__ __forceinline__ float blo(unsigned u) { return __uint_as_float(u << 16); }
__device__ __forceinline__ float bhi(unsigned u) { return __uint_as_float(u & 0xffff0000u); }
__device__ __forceinline__ unsigned short fbits(float v) {
  union { bf16 b; unsigned short u; } c; c.b = f2b(v); return c.u;
}
__device__ __forceinline__ float ubf(unsigned short u) {
  return __uint_as_float(((unsigned)u) << 16);
}
// async global->LDS, 16B per lane. LDS dest must be wave-uniform base + lane*16.
__device__ __forceinline__ void gld16(const void* g, void* l) {
  __builtin_amdgcn_global_load_lds((const unsigned int*)g, (unsigned int*)l, 16, 0, 0);
}

// ---- weight prep ----
__global__ __launch_bounds__(256) void k_prep(
    const float* __restrict__ W1, const float* __restrict__ W2,
    const float* __restrict__ W3, float* __restrict__ W1t,
    short* __restrict__ W2f, short* __restrict__ W2u,
    short* __restrict__ W3m, short* __restrict__ W3u) {
  int i = blockIdx.x * 256 + threadIdx.x;
  if (i < 4800) {
    int oc = i / 75, k = i % 75;
    W1t[k * 64 + oc] = W1[i];
  }
  if (i < 204800) {
    int oc = i / 1600, k = i % 1600, ic = k / 25, tap = k % 25;
    float w = W2[i];
    unsigned short hi = fbits(w);
    unsigned short lo = fbits(w - ubf(hi));
    W2f[(tap * 128 + oc) * 64 + (ic ^ ((oc & 7) << 3))] = (short)hi;
    W2f[204800 + (tap * 128 + oc) * 64 + (ic ^ ((oc & 7) << 3))] = (short)lo;
    W2u[(tap * 64 + ic) * 128 + (oc ^ ((ic & 7) << 3))] = (short)hi;
  }
  if (i < 294912) {
    int oc = i / 1152, k = i % 1152, ic = k / 9, tap = k % 9;
    float w = W3[i];
    unsigned short hi = fbits(w);
    unsigned short lo = fbits(w - ubf(hi));
    W3m[(tap * 256 + oc) * 128 + (ic ^ ((oc & 7) << 3))] = (short)hi;
    W3m[294912 + (tap * 256 + oc) * 128 + (ic ^ ((oc & 7) << 3))] = (short)lo;
    W3u[(tap * 128 + ic) * 256 + (oc ^ ((ic & 7) << 3))] = (short)hi;
  }
}

// ---- conv1 (LDS-staged, 512 threads): h1T = relu(conv1(x)) ----
// block=(bt,oy), oy in [0,14). Wave w8: oc-group w8&3, h-half w8>>2.
__global__ __launch_bounds__(512, 1) void k_conv1s(
    const float* __restrict__ x, const float* __restrict__ W1t,
    const float* __restrict__ b1, bf16* __restrict__ h1T) {
  __shared__ float xs[480 * 66];  // [f 480 = ic*160+ky*32+x][col 64 (+2 pad)]
  __shared__ float ws[4800];      // [tap 75][oc 64]
  int bt = blockIdx.x, oy = blockIdx.y;
  int tid = threadIdx.x, lane = tid & 63, w8 = tid >> 6;
  int wv = w8 & 3, h = w8 >> 2;
  for (int i = tid; i < 4800; i += 512) ws[i] = W1t[i];
#pragma unroll
  for (int r = 0; r < 15; ++r) {
    int idx = r * 512 + tid;
    int col = idx / 120, q = idx % 120;
    int ic = q / 40, rem = q % 40;
    float4 v = *(const float4*)(x + (size_t)(bt * 64 + col) * 3072 +
                                ic * 1024 + oy * 64 + rem * 4);
    float* d = xs + (ic * 160 + rem * 4) * 66 + col;
    d[0] = v.x;
    d[66] = v.y;
    d[132] = v.z;
    d[198] = v.w;
  }
  __syncthreads();
  int oc0 = wv * 16;
  float acc[7][16];
#pragma unroll
  for (int o = 0; o < 7; ++o)
#pragma unroll
    for (int j = 0; j < 16; ++j) acc[o][j] = b1[oc0 + j];
  for (int ic = 0; ic < 3; ++ic)
    for (int ky = 0; ky < 5; ++ky) {
#pragma unroll
      for (int kx = 0; kx < 5; ++kx) {
        const float* wp = ws + ((ic * 25 + ky * 5 + kx) << 6) + oc0;
        float4 w0 = *(const float4*)(wp);
        float4 w1 = *(const float4*)(wp + 4);
        float4 w2 = *(const float4*)(wp + 8);
        float4 w3 = *(const float4*)(wp + 12);
        const float* xr = xs + (ic * 160 + ky * 32 + kx) * 66 + lane;
        float xv[7];
#pragma unroll
        for (int o = 0; o < 7; ++o) xv[o] = xr[(2 * (h * 7 + o)) * 66];
#pragma unroll
        for (int o = 0; o < 7; ++o) {
          float e = xv[o];
          acc[o][0] += e * w0.x;  acc[o][1] += e * w0.y;
          acc[o][2] += e * w0.z;  acc[o][3] += e * w0.w;
          acc[o][4] += e * w1.x;  acc[o][5] += e * w1.y;
          acc[o][6] += e * w1.z;  acc[o][7] += e * w1.w;
          acc[o][8] += e * w2.x;  acc[o][9] += e * w2.y;
          acc[o][10] += e * w2.z; acc[o][11] += e * w2.w;
          acc[o][12] += e * w3.x; acc[o][13] += e * w3.y;
          acc[o][14] += e * w3.z; acc[o][15] += e * w3.w;
        }
      }
    }
#pragma unroll
  for (int o = 0; o < 7; ++o) {
    int pix = oy * 14 + h * 7 + o;
    size_t tbase = ((size_t)(pix * 32 + bt)) << 12;
#pragma unroll
    for (int q = 0; q < 4; ++q) {
      ushort4 pk;
      pk.x = fbits(fmaxf(acc[o][q * 4 + 0], 0.f));
      pk.y = fbits(fmaxf(acc[o][q * 4 + 1], 0.f));
      pk.z = fbits(fmaxf(acc[o][q * 4 + 2], 0.f));
      pk.w = fbits(fmaxf(acc[o][q * 4 + 3], 0.f));
      int ocr = oc0 + q * 4;
      size_t off = tbase + lane * 64 + (ocr ^ ((lane & 7) << 3));
      *(ushort4*)(h1T + off) = pk;
    }
  }
}

// ---- fwd2 (MFMA, 2-cb): p2T = relu(conv2(in1)); fused e2T ----
// grid 400 (1-D): xcd=bid&7, j=bid>>3 (0..49), cbp=xcd*2+(j&1), pos=j>>1
__global__ __launch_bounds__(256) void k_fwd2m(
    const bf16* __restrict__ in1, const short* __restrict__ W2f,
    const float* __restrict__ b2, bf16* __restrict__ p2T,
    const bf16* __restrict__ t2e, bf16* __restrict__ e2T, int einit) {
  __shared__ __align__(16) short As0[8192];     // hi [128 oc][64 ic]
  __shared__ __align__(16) short As1[8192];     // lo
  __shared__ __align__(16) short Bs[2][4096];   // [cb][64 col][64 ic]
  int bid = blockIdx.x;
  int j = bid >> 3;
  int cbp = (bid & 7) * 2 + (j & 1), pos = j >> 1;
  int cb0 = cbp * 2;
  int tid = threadIdx.x, lane = tid & 63, wv = tid >> 6;
  int oy = pos / 5, ox = pos % 5;
  float4v acc[2][2][4];
#pragma unroll
  for (int c = 0; c < 2; ++c)
#pragma unroll
    for (int m = 0; m < 2; ++m)
#pragma unroll
      for (int n = 0; n < 4; ++n) acc[c][m][n] = (float4v){0.f, 0.f, 0.f, 0.f};

  for (int tap = 0; tap < 25; ++tap) {
    int ky = tap / 5, kx = tap % 5;
    int ipix = (2 * oy + ky) * 14 + (2 * ox + kx);
    __syncthreads();
    {
      const uint4* bs0 = (const uint4*)(in1 + (((size_t)(ipix * 32 + cb0)) << 12));
      const uint4* bs1 = (const uint4*)(in1 + (((size_t)(ipix * 32 + cb0 + 1)) << 12));
      uint4* bd = (uint4*)Bs;
      gld16(&bs0[tid], &bd[tid]);
      gld16(&bs0[tid + 256], &bd[tid + 256]);
      gld16(&bs1[tid], &bd[tid + 512]);
      gld16(&bs1[tid + 256], &bd[tid + 768]);
      const uint4* ah = (const uint4*)(W2f + tap * 8192);
      const uint4* al = (const uint4*)(W2f + 204800 + tap * 8192);
      uint4* dh = (uint4*)As0;
      uint4* dl = (uint4*)As1;
#pragma unroll
      for (int p = 0; p < 4; ++p) {
        gld16(&ah[tid + p * 256], &dh[tid + p * 256]);
        gld16(&al[tid + p * 256], &dl[tid + p * 256]);
      }
    }
    __syncthreads();
#pragma unroll
    for (int ks = 0; ks < 2; ++ks) {
      int ic0 = ks * 32 + ((lane >> 4) << 3);
      short8v bfr[2][4];
#pragma unroll
      for (int c = 0; c < 2; ++c)
#pragma unroll
        for (int n = 0; n < 4; ++n) {
          int colv = n * 16 + (lane & 15);
          bfr[c][n] = *(const short8v*)(&Bs[c][0] + colv * 64 + (ic0 ^ ((colv & 7) << 3)));
        }
#pragma unroll
      for (int m = 0; m < 2; ++m) {
        int row = wv * 32 + m * 16 + (lane & 15);
        int aoff = row * 64 + (ic0 ^ ((row & 7) << 3));
        short8v ah = *(const short8v*)(As0 + aoff);
        short8v al = *(const short8v*)(As1 + aoff);
#pragma unroll
        for (int c = 0; c < 2; ++c)
#pragma unroll
          for (int n = 0; n < 4; ++n) {
            acc[c][m][n] = __builtin_amdgcn_mfma_f32_16x16x32_bf16(ah, bfr[c][n], acc[c][m][n], 0, 0, 0);
            acc[c][m][n] = __builtin_amdgcn_mfma_f32_16x16x32_bf16(al, bfr[c][n], acc[c][m][n], 0, 0, 0);
          }
      }
    }
  }
#pragma unroll
  for (int c = 0; c < 2; ++c) {
    size_t tb2 = ((size_t)(pos * 32 + cb0 + c)) << 13;
#pragma unroll
    for (int m = 0; m < 2; ++m) {
      int ocb = wv * 32 + m * 16 + ((lane >> 4) << 2);
      float4 bv = *(const float4*)(b2 + ocb);
#pragma unroll
      for (int n = 0; n < 4; ++n) {
        int colv = n * 16 + (lane & 15);
        ushort4 pk;
        pk.x = fbits(fmaxf(acc[c][m][n][0] + bv.x, 0.f));
        pk.y = fbits(fmaxf(acc[c][m][n][1] + bv.y, 0.f));
        pk.z = fbits(fmaxf(acc[c][m][n][2] + bv.z, 0.f));
        pk.w = fbits(fmaxf(acc[c][m][n][3] + bv.w, 0.f));
        size_t off = tb2 + colv * 128 + (ocb ^ ((colv & 7) << 3));
        *(ushort4*)(p2T + off) = pk;
        if (einit) {
          ushort4 z = {0, 0, 0, 0};
          *(ushort4*)(e2T + off) = z;
        } else {
          ushort4 tv = *(const ushort4*)(t2e + off);
          ushort4 ev;
          float p0, t0;
          p0 = ubf(pk.x); t0 = ubf(tv.x); ev.x = fbits(p0 > 0.f ? t0 - p0 : 0.f);
          p0 = ubf(pk.y); t0 = ubf(tv.y); ev.y = fbits(p0 > 0.f ? t0 - p0 : 0.f);
          p0 = ubf(pk.z); t0 = ubf(tv.z); ev.z = fbits(p0 > 0.f ? t0 - p0 : 0.f);
          p0 = ubf(pk.w); t0 = ubf(tv.w); ev.w = fbits(p0 > 0.f ? t0 - p0 : 0.f);
          *(ushort4*)(e2T + off) = ev;
        }
      }
    }
  }
}

// ---- upd1 (MFMA, hi-only, 2-cb): g1 = conv2^T(e2T); t1w = upd(t1r) ----
// grid 3136 (1-D): xcd=bid&7, j=bid>>3 (0..391), cbp=xcd*2+(j&1), pix=j>>1
__global__ __launch_bounds__(256) void k_upd1m(
    const bf16* __restrict__ e2T, const short* __restrict__ W2u,
    const bf16* __restrict__ h1T, const bf16* __restrict__ t1r,
    bf16* __restrict__ t1w) {
  __shared__ __align__(16) short As0[8192];    // hi [64 ic][128 oc]
  __shared__ __align__(16) short Es[2][8192];  // [cb][64 col][128 oc]
  int bid = blockIdx.x;
  int j = bid >> 3;
  int cbp = (bid & 7) * 2 + (j & 1), pix = j >> 1;
  int cb0 = cbp * 2;
  int tid = threadIdx.x, lane = tid & 63, wv = tid >> 6;
  int iy = pix / 14, ix = pix % 14;
  float4v acc[2][4];
#pragma unroll
  for (int c = 0; c < 2; ++c)
#pragma unroll
    for (int n = 0; n < 4; ++n) acc[c][n] = (float4v){0.f, 0.f, 0.f, 0.f};

  for (int ky = iy & 1; ky <= 4; ky += 2) {
    int oy = (iy - ky) >> 1;
    if (oy < 0 || oy > 4) continue;
    for (int kx = ix & 1; kx <= 4; kx += 2) {
      int ox = (ix - kx) >> 1;
      if (ox < 0 || ox > 4) continue;
      int erow = oy * 5 + ox, tap = ky * 5 + kx;
      __syncthreads();
      {
        const uint4* es0 = (const uint4*)(e2T + (((size_t)(erow * 32 + cb0)) << 13));
        const uint4* es1 = (const uint4*)(e2T + (((size_t)(erow * 32 + cb0 + 1)) << 13));
        uint4* ed = (uint4*)Es;
        const uint4* ah = (const uint4*)(W2u + tap * 8192);
        uint4* dh = (uint4*)As0;
#pragma unroll
        for (int p = 0; p < 4; ++p) {
          gld16(&es0[tid + p * 256], &ed[tid + p * 256]);
          gld16(&es1[tid + p * 256], &ed[tid + p * 256 + 1024]);
          gld16(&ah[tid + p * 256], &dh[tid + p * 256]);
        }
      }
      __syncthreads();
#pragma unroll
      for (int ks = 0; ks < 4; ++ks) {
        int oc0 = ks * 32 + ((lane >> 4) << 3);
        int row = wv * 16 + (lane & 15);
        int aoff = row * 128 + (oc0 ^ ((row & 7) << 3));
        short8v ah = *(const short8v*)(As0 + aoff);
#pragma unroll
        for (int c = 0; c < 2; ++c)
#pragma unroll
          for (int n = 0; n < 4; ++n) {
            int colv = n * 16 + (lane & 15);
            short8v ef = *(const short8v*)(&Es[c][0] + colv * 128 + (oc0 ^ ((colv & 7) << 3)));
            acc[c][n] = __builtin_amdgcn_mfma_f32_16x16x32_bf16(ah, ef, acc[c][n], 0, 0, 0);
          }
      }
    }
  }
  int icb = wv * 16 + ((lane >> 4) << 2);
#pragma unroll
  for (int c = 0; c < 2; ++c) {
    size_t tb1 = ((size_t)(pix * 32 + cb0 + c)) << 12;
#pragma unroll
    for (int n = 0; n < 4; ++n) {
      int colv = n * 16 + (lane & 15);
      size_t off = tb1 + colv * 64 + (icb ^ ((colv & 7) << 3));
      ushort4 tv = *(const ushort4*)(t1r + off);
      ushort4 hv = *(const ushort4*)(h1T + off);
      ushort4 rp;
      float t0, h0;
      t0 = ubf(tv.x); h0 = ubf(hv.x);
      rp.x = fbits(t0 - 0.07f * (t0 - h0) + 0.07f * acc[c][n][0]);
      t0 = ubf(tv.y); h0 = ubf(hv.y);
      rp.y = fbits(t0 - 0.07f * (t0 - h0) + 0.07f * acc[c][n][1]);
      t0 = ubf(tv.z); h0 = ubf(hv.z);
      rp.z = fbits(t0 - 0.07f * (t0 - h0) + 0.07f * acc[c][n][2]);
      t0 = ubf(tv.w); h0 = ubf(hv.w);
      rp.w = fbits(t0 - 0.07f * (t0 - h0) + 0.07f * acc[c][n][3]);
      *(ushort4*)(t1w + off) = rp;
    }
  }
}

// ---- fwd3 (MFMA): p3T = relu(conv3(in2)); fused e3T = mask(p3)*(t3e-p3) ----
// grid 512 (1-D): xcd=bid&7, j=bid>>3, cb=xcd*4+(j&3), r=j>>2, pos=r&3, och=r>>2
__global__ __launch_bounds__(256) void k_fwd3m(
    const bf16* __restrict__ in2, const short* __restrict__ W3m,
    const float* __restrict__ b3, bf16* __restrict__ p3T,
    const bf16* __restrict__ t3e, bf16* __restrict__ e3T, int einit) {
  __shared__ __align__(16) short As0[8192];  // hi [64 oc][128 ic]
  __shared__ __align__(16) short As1[8192];  // lo
  __shared__ __align__(16) short Bs[8192];   // [64 col][128 ic]
  int bid = blockIdx.x;
  int j = bid >> 3;
  int cb = (bid & 7) * 4 + (j & 3);
  int r = j >> 2;
  int pos = r & 3, och = r >> 2;
  int tid = threadIdx.x, lane = tid & 63, wv = tid >> 6;
  int oy = pos >> 1, ox = pos & 1;
  float4v acc[4];
#pragma unroll
  for (int n = 0; n < 4; ++n) acc[n] = (float4v){0.f, 0.f, 0.f, 0.f};

  for (int tap = 0; tap < 9; ++tap) {
    int ky = tap / 3, kx = tap % 3;
    int irow = (2 * oy + ky) * 5 + (2 * ox + kx);
    __syncthreads();
    {
      const uint4* bs = (const uint4*)(in2 + (((size_t)(irow * 32 + cb)) << 13));
      uint4* bd = (uint4*)Bs;
#pragma unroll
      for (int p = 0; p < 4; ++p) gld16(&bs[tid + p * 256], &bd[tid + p * 256]);
      const uint4* ah = (const uint4*)(W3m + ((size_t)tap * 256 + och * 64) * 128);
      const uint4* al = (const uint4*)(W3m + 294912 + ((size_t)tap * 256 + och * 64) * 128);
      uint4* dh = (uint4*)As0;
      uint4* dl = (uint4*)As1;
#pragma unroll
      for (int p = 0; p < 4; ++p) {
        gld16(&ah[tid + p * 256], &dh[tid + p * 256]);
        gld16(&al[tid + p * 256], &dl[tid + p * 256]);
      }
    }
    __syncthreads();
#pragma unroll
    for (int ks = 0; ks < 4; ++ks) {
      int ic0 = ks * 32 + ((lane >> 4) << 3);
      short8v bfr[4];
#pragma unroll
      for (int n = 0; n < 4; ++n) {
        int colv = n * 16 + (lane & 15);
        bfr[n] = *(const short8v*)(Bs + colv * 128 + (ic0 ^ ((colv & 7) << 3)));
      }
      int row = wv * 16 + (lane & 15);
      int aoff = row * 128 + (ic0 ^ ((row & 7) << 3));
      short8v ah = *(const short8v*)(As0 + aoff);
      short8v al = *(const short8v*)(As1 + aoff);
#pragma unroll
      for (int n = 0; n < 4; ++n) {
        acc[n] = __builtin_amdgcn_mfma_f32_16x16x32_bf16(ah, bfr[n], acc[n], 0, 0, 0);
        acc[n] = __builtin_amdgcn_mfma_f32_16x16x32_bf16(al, bfr[n], acc[n], 0, 0, 0);
      }
    }
  }
  size_t tb3 = ((size_t)(pos * 32 + cb)) << 14;
  int ocg = och * 64 + wv * 16 + ((lane >> 4) << 2);
  float4 bv = *(const float4*)(b3 + ocg);
#pragma unroll
  for (int n = 0; n < 4; ++n) {
    int colv = n * 16 + (lane & 15);
    ushort4 pk;
    pk.x = fbits(fmaxf(acc[n][0] + bv.x, 0.f));
    pk.y = fbits(fmaxf(acc[n][1] + bv.y, 0.f));
    pk.z = fbits(fmaxf(acc[n][2] + bv.z, 0.f));
    pk.w = fbits(fmaxf(acc[n][3] + bv.w, 0.f));
    size_t off = tb3 + colv * 256 + (ocg ^ ((colv & 7) << 3));
    *(ushort4*)(p3T + off) = pk;
    if (einit) {
      ushort4 z = {0, 0, 0, 0};
      *(ushort4*)(e3T + off) = z;
    } else {
      ushort4 tv = *(const ushort4*)(t3e + off);
      ushort4 ev;
      float p0, t0;
      p0 = ubf(pk.x); t0 = ubf(tv.x); ev.x = fbits(p0 > 0.f ? t0 - p0 : 0.f);
      p0 = ubf(pk.y); t0 = ubf(tv.y); ev.y = fbits(p0 > 0.f ? t0 - p0 : 0.f);
      p0 = ubf(pk.z); t0 = ubf(tv.z); ev.z = fbits(p0 > 0.f ? t0 - p0 : 0.f);
      p0 = ubf(pk.w); t0 = ubf(tv.w); ev.w = fbits(p0 > 0.f ? t0 - p0 : 0.f);
      *(ushort4*)(e3T + off) = ev;
    }
  }
}

// ---- upd2 (MFMA, hi-only, 2-cb): g2 = conv3^T(e3T); t2w = upd(t2r) ----
// grid 400 (1-D): xcd=bid&7, j=bid>>3 (0..49), cbp=xcd*2+(j&1), pix=j>>1
// LDS 48KB (Es[2] 32KB + As0 16KB) -> 3 blocks/CU; weight stage shared.
__global__ __launch_bounds__(256) void k_upd2m(
    const bf16* __restrict__ e3T, const bf16* __restrict__ p2T,
    const short* __restrict__ W3u, const bf16* __restrict__ t2r,
    bf16* __restrict__ t2w) {
  __shared__ __align__(16) short Es[2][8192];  // [cb][64 col][128 oc_local]
  __shared__ __align__(16) short As0[16384];   // hi [128 ic][128 oc_local]
  int bid = blockIdx.x;
  int j = bid >> 3;
  int cbp = (bid & 7) * 2 + (j & 1), pix = j >> 1;
  int cb0 = cbp * 2;
  int tid = threadIdx.x, lane = tid & 63, wv = tid >> 6;
  int iy = pix / 5, ix = pix % 5;
  float4v acc[2][2][4];
#pragma unroll
  for (int c = 0; c < 2; ++c)
#pragma unroll
    for (int m = 0; m < 2; ++m)
#pragma unroll
      for (int n = 0; n < 4; ++n) acc[c][m][n] = (float4v){0.f, 0.f, 0.f, 0.f};

  for (int ky = iy & 1; ky <= 2; ky += 2) {
    int oy = (iy - ky) >> 1;
    if (oy < 0 || oy > 1) continue;
    for (int kx = ix & 1; kx <= 2; kx += 2) {
      int ox = (ix - kx) >> 1;
      if (ox < 0 || ox > 1) continue;
      int erow = oy * 2 + ox, tap = ky * 3 + kx;
      for (int occ = 0; occ < 2; ++occ) {
        __syncthreads();
        {
          size_t tb0 = ((size_t)(erow * 32 + cb0)) << 14;
          size_t tb1 = ((size_t)(erow * 32 + cb0 + 1)) << 14;
          uint4* ed = (uint4*)Es;
#pragma unroll
          for (int p = 0; p < 4; ++p) {
            int fi = tid + p * 256;
            int colr = fi >> 4, q = fi & 15;
            size_t goff = colr * 256 + occ * 128 + q * 8;
            gld16(e3T + tb0 + goff, &ed[fi]);
            gld16(e3T + tb1 + goff, &ed[fi + 1024]);
          }
          uint4* dh = (uint4*)As0;
#pragma unroll
          for (int p = 0; p < 8; ++p) {
            int fi = tid + p * 256;
            int icr = fi >> 4, q = fi & 15;
            size_t srcoff = ((size_t)(tap * 128 + icr)) * 256 + occ * 128 + q * 8;
            gld16(W3u + srcoff, &dh[fi]);
          }
        }
        __syncthreads();
#pragma unroll
        for (int ks = 0; ks < 4; ++ks) {
          int oc0 = ks * 32 + ((lane >> 4) << 3);
          short8v efr[2][4];
#pragma unroll
          for (int c = 0; c < 2; ++c)
#pragma unroll
            for (int n = 0; n < 4; ++n) {
              int colv = n * 16 + (lane & 15);
              efr[c][n] = *(const short8v*)(&Es[c][0] + colv * 128 + (oc0 ^ ((colv & 7) << 3)));
            }
#pragma unroll
          for (int m = 0; m < 2; ++m) {
            int icr = wv * 32 + m * 16 + (lane & 15);
            int aoff = icr * 128 + (oc0 ^ ((icr & 7) << 3));
            short8v ah = *(const short8v*)(As0 + aoff);
#pragma unroll
            for (int c = 0; c < 2; ++c)
#pragma unroll
              for (int n = 0; n < 4; ++n) {
                acc[c][m][n] = __builtin_amdgcn_mfma_f32_16x16x32_bf16(ah, efr[c][n], acc[c][m][n], 0, 0, 0);
              }
          }
        }
      }
    }
  }
#pragma unroll
  for (int c = 0; c < 2; ++c) {
    size_t tb2 = ((size_t)(pix * 32 + cb0 + c)) << 13;
#pragma unroll
    for (int m = 0; m < 2; ++m) {
      int icr = wv * 32 + m * 16 + ((lane >> 4) << 2);
#pragma unroll
      for (int n = 0; n < 4; ++n) {
        int colv = n * 16 + (lane & 15);
        size_t off = tb2 + colv * 128 + (icr ^ ((colv & 7) << 3));
        ushort4 tv = *(const ushort4*)(t2r + off);
        ushort4 pv = *(const ushort4*)(p2T + off);
        ushort4 rp;
        float t0, p0;
        t0 = ubf(tv.x); p0 = ubf(pv.x);
        rp.x = fbits(t0 - 0.07f * (t0 - p0) + 0.07f * acc[c][m][n][0]);
        t0 = ubf(tv.y); p0 = ubf(pv.y);
        rp.y = fbits(t0 - 0.07f * (t0 - p0) + 0.07f * acc[c][m][n][1]);
        t0 = ubf(tv.z); p0 = ubf(pv.z);
        rp.z = fbits(t0 - 0.07f * (t0 - p0) + 0.07f * acc[c][m][n][2]);
        t0 = ubf(tv.w); p0 = ubf(pv.w);
        rp.w = fbits(t0 - 0.07f * (t0 - p0) + 0.07f * acc[c][m][n][3]);
        *(ushort4*)(t2w + off) = rp;
      }
    }
  }
}

// ---- fu3: p4 = t3r @ W4^T + b4 (all-lane butterfly); softmax; e4;
//      g3 = e4 @ W4; t3w = upd(t3r).
//      w4s bank-conflict-free: phys(k) = k + ((k>>7)<<2), row stride 1056. ----
__global__ __launch_bounds__(256) void k_fu3(
    const float* __restrict__ gt, const float* __restrict__ W4,
    const float* __restrict__ b4, const bf16* __restrict__ p3T,
    const bf16* __restrict__ t3r, bf16* __restrict__ t3w) {
  __shared__ __align__(16) float w4s[10560];  // 10 rows x 1056 (swizzled)
  int tid = threadIdx.x;
  for (int i = tid; i < 10240; i += 256) {
    int o = i >> 10, k = i & 1023;
    w4s[o * 1056 + k + ((k >> 7) << 2)] = W4[i];
  }
  __syncthreads();
  int c = blockIdx.x * 8 + (tid >> 5);
  int cb = c >> 6, colL = c & 63, subk = tid & 31;
  int pos = subk & 3, ch0 = (subk >> 2) * 32;
  int xc = (colL & 7) << 3;
  size_t boff = (((size_t)(pos * 32 + cb)) << 14) + colL * 256 + ch0;
  const bf16* trd = t3r + boff;
  const bf16* pb = p3T + boff;
  uint4 tq[4];
#pragma unroll
  for (int q = 0; q < 4; ++q) tq[q] = *(const uint4*)(trd + q * 8);
  float acc[10] = {};
#pragma unroll
  for (int q = 0; q < 4; ++q) {
    unsigned wds[4] = {tq[q].x, tq[q].y, tq[q].z, tq[q].w};
    int chb = (ch0 + q * 8) ^ xc;
#pragma unroll
    for (int h = 0; h < 4; ++h) {
      float v0 = blo(wds[h]), v1 = bhi(wds[h]);
      int k0 = (chb + 2 * h) * 4 + pos;
      int ks = k0 + ((k0 >> 7) << 2);  // k0%128<=123 so +4 stays in-block
#pragma unroll
      for (int o = 0; o < 10; ++o)
        acc[o] += v0 * w4s[o * 1056 + ks] + v1 * w4s[o * 1056 + ks + 4];
    }
  }
#pragma unroll
  for (int off = 16; off > 0; off >>= 1)
#pragma unroll
    for (int o = 0; o < 10; ++o) acc[o] += __shfl_xor(acc[o], off, 32);
  float pv[10], m = -1e30f;
#pragma unroll
  for (int o = 0; o < 10; ++o) {
    pv[o] = acc[o] + b4[o];
    m = fmaxf(m, pv[o]);
  }
  float s = 0.f;
#pragma unroll
  for (int o = 0; o < 10; ++o) {
    pv[o] = __expf(pv[o] - m);
    s += pv[o];
  }
  float inv = 1.f / s;
  float e4[10];
#pragma unroll
  for (int o = 0; o < 10; ++o)
    e4[o] = (gt[(size_t)c * 10 + o] - pv[o] * inv) * 0.5f;
  bf16* tb = t3w + boff;
#pragma unroll
  for (int q = 0; q < 4; ++q) {
    uint4 pq = *(const uint4*)(pb + q * 8);
    unsigned tw[4] = {tq[q].x, tq[q].y, tq[q].z, tq[q].w};
    unsigned pw[4] = {pq.x, pq.y, pq.z, pq.w};
    int chb = (ch0 + q * 8) ^ xc;
    unsigned ro[4];
#pragma unroll
    for (int h = 0; h < 4; ++h) {
      int k0 = (chb + 2 * h) * 4 + pos;
      int ks = k0 + ((k0 >> 7) << 2);
      float g0 = 0.f, g1 = 0.f;
#pragma unroll
      for (int o = 0; o < 10; ++o) {
        g0 += e4[o] * w4s[o * 1056 + ks];
        g1 += e4[o] * w4s[o * 1056 + ks + 4];
      }
      float t0 = blo(tw[h]), p0 = blo(pw[h]);
      float t1 = bhi(tw[h]), p1 = bhi(pw[h]);
      float r0 = t0 - 0.07f * (t0 - p0) + 0.07f * g0;
      float r1 = t1 - 0.07f * (t1 - p1) + 0.07f * g1;
      ro[h] = (unsigned)fbits(r0) | ((unsigned)fbits(r1) << 16);
    }
    uint4 rv = {ro[0], ro[1], ro[2], ro[3]};
    *(uint4*)(tb + q * 8) = rv;
  }
}

// ---- k_tr1: t1 section gather (contiguous slab reads, LDS rotate) ----
__global__ __launch_bounds__(256) void k_tr1(
    const bf16* __restrict__ t1T, float* __restrict__ out) {
  __shared__ short lds[2 * 64 * 224];
  int cb = blockIdx.x, c0 = blockIdx.y * 2;
  int tid = threadIdx.x;
  for (int i = tid; i < 3136; i += 256) {
    int pix = i >> 4, q = i & 15;
    int colL = q >> 3, chb = (q & 7) << 3;
    int col = c0 + colL;
    uint4 v = *(const uint4*)(t1T + (((size_t)(pix * 32 + cb)) << 12) + col * 64 + chb);
    int icb = chb ^ ((col & 7) << 3);
    int posX = pix ^ (((icb >> 3) & 7) << 2);
    short* d = lds + (colL * 64 + icb) * 224 + posX;
    const short* vs = (const short*)&v;
#pragma unroll
    for (int j = 0; j < 8; ++j) d[j * 224] = vs[j];
  }
  __syncthreads();
  for (int i = tid; i < 6272; i += 256) {
    int colL = i / 3136, m = i % 3136;
    int ic = m / 49, pp = m % 49;
    int posX = (pp * 4) ^ (((ic >> 3) & 7) << 2);
    const short* s = lds + (colL * 64 + ic) * 224 + posX;
    float4 o;
    o.x = ubf((unsigned short)s[0]);
    o.y = ubf((unsigned short)s[1]);
    o.z = ubf((unsigned short)s[2]);
    o.w = ubf((unsigned short)s[3]);
    *(float4*)(out + ((size_t)(cb * 64 + c0 + colL)) * 16768 + m * 4) = o;
  }
}

// ---- k_tr2: t2 section gather ----
__global__ __launch_bounds__(256) void k_tr2(
    const bf16* __restrict__ t2T, float* __restrict__ out) {
  __shared__ short lds[4 * 128 * 32];
  int cb = blockIdx.x, c0 = blockIdx.y * 4;
  int tid = threadIdx.x;
  for (int i = tid; i < 1600; i += 256) {
    int pos = i >> 6, q = i & 63;
    int colL = q >> 4, chb = (q & 15) << 3;
    int col = c0 + colL;
    uint4 v = *(const uint4*)(t2T + (((size_t)(pos * 32 + cb)) << 13) + col * 128 + chb);
    int ocb = chb ^ ((col & 7) << 3);
    int posX = pos ^ (((ocb >> 3) & 7) << 2);
    short* d = lds + (colL * 128 + ocb) * 32 + posX;
    const short* vs = (const short*)&v;
#pragma unroll
    for (int j = 0; j < 8; ++j) d[j * 32] = vs[j];
  }
  __syncthreads();
  for (int i = tid; i < 3200; i += 256) {
    int colL = i / 800, m = i % 800;
    int f0 = m * 4;
    float4 o;
    float* po = &o.x;
#pragma unroll
    for (int t = 0; t < 4; ++t) {
      int f = f0 + t;
      int oc = f / 25, pos = f % 25;
      int posX = pos ^ (((oc >> 3) & 7) << 2);
      po[t] = ubf((unsigned short)lds[(colL * 128 + oc) * 32 + posX]);
    }
    *(float4*)(out + ((size_t)(cb * 64 + c0 + colL)) * 16768 + 12544 + f0) = o;
  }
}

// ---- k_tr3: t3 section gather, register transpose ----
__global__ __launch_bounds__(256) void k_tr3(
    const bf16* __restrict__ t3T, float* __restrict__ out) {
  int tid = threadIdx.x;
  int sample = blockIdx.x * 8 + (tid >> 5);
  int cb = sample >> 6, col = sample & 63;
  int chb = (tid & 31) << 3;
  int icb = chb ^ ((col & 7) << 3);
  uint4 v[4];
#pragma unroll
  for (int pos = 0; pos < 4; ++pos)
    v[pos] = *(const uint4*)(t3T + (((size_t)(pos * 32 + cb)) << 14) + col * 256 + chb);
  const unsigned short* s0 = (const unsigned short*)&v[0];
  const unsigned short* s1 = (const unsigned short*)&v[1];
  const unsigned short* s2 = (const unsigned short*)&v[2];
  const unsigned short* s3 = (const unsigned short*)&v[3];
  float* ob = out + (size_t)sample * 16768 + 15744 + icb * 4;
#pragma unroll
  for (int j = 0; j < 8; ++j) {
    float4 o;
    o.x = ubf(s0[j]);
    o.y = ubf(s1[j]);
    o.z = ubf(s2[j]);
    o.w = ubf(s3[j]);
    *(float4*)(ob + j * 4) = o;
  }
}

extern "C" void kernel_launch(void* const* d_in, const int* in_sizes, int n_in,
                              void* d_out, int out_size, void* d_ws,
                              size_t ws_size, hipStream_t stream) {
  const float* x  = (const float*)d_in[0];
  const float* gt = (const float*)d_in[1];
  const float* W1 = (const float*)d_in[2];
  const float* b1 = (const float*)d_in[3];
  const float* W2 = (const float*)d_in[4];
  const float* b2 = (const float*)d_in[5];
  const float* W3 = (const float*)d_in[6];
  const float* b3 = (const float*)d_in[7];
  const float* W4 = (const float*)d_in[8];
  const float* b4 = (const float*)d_in[9];
  float* out = (float*)d_out;

  bf16* h1T = (bf16*)d_ws;
  bf16* t1T = h1T + 25690112ull;
  bf16* t2T = t1T + 25690112ull;
  bf16* p2T = t2T + 6553600ull;
  bf16* t3T = p2T + 6553600ull;
  bf16* p3T = t3T + 2097152ull;
  float* p4f = (float*)(p3T + 2097152ull);  // unused (kept for layout)
  float* W1t = p4f + 20480;
  short* W3m = (short*)(W1t + 4800);
  short* W3u = W3m + 589824;
  short* W2f = W3u + 589824;
  short* W2u = W2f + 409600;
  // e2T/e3T (13.1 + 4.2 MB bf16) live in d_out (134 MB), dead until k_tr*.
  bf16* e2T = (bf16*)out;
  bf16* e3T = e2T + 6553600ull;

  dim3 blk(256);

  k_prep<<<1152, blk, 0, stream>>>(W1, W2, W3, W1t, W2f, W2u, W3m, W3u);
  k_conv1s<<<dim3(32, 14), dim3(512), 0, stream>>>(x, W1t, b1, h1T);
  k_fwd2m<<<400, blk, 0, stream>>>(h1T, W2f, b2, p2T, p2T, e2T, 1);
  k_fwd3m<<<512, blk, 0, stream>>>(p2T, W3m, b3, p3T, p3T, e3T, 1);

  for (int it = 0; it < 25; ++it) {
    const bf16* t1r = (it == 0) ? h1T : t1T;
    const bf16* t2r = (it == 0) ? p2T : t2T;
    const bf16* t3r = (it == 0) ? p3T : t3T;
    k_upd1m<<<3136, blk, 0, stream>>>(e2T, W2u, h1T, t1r, t1T);
    k_upd2m<<<400, blk, 0, stream>>>(e3T, p2T, W3u, t2r, t2T);
    k_fu3<<<256, blk, 0, stream>>>(gt, W4, b4, p3T, t3r, t3T);
    if (it < 24) {
      k_fwd2m<<<400, blk, 0, stream>>>(t1T, W2f, b2, p2T, t2T, e2T, 0);
      k_fwd3m<<<512, blk, 0, stream>>>(t2T, W3m, b3, p3T, t3T, e3T, 0);
    }
  }
  k_tr1<<<dim3(32, 32), blk, 0, stream>>>(t1T, out);
  k_tr2<<<dim3(32, 16), blk, 0, stream>>>(t2T, out);
  k_tr3<<<256, blk, 0, stream>>>(t3T, out);
}

// Round 14
// 3383.483 us; speedup vs baseline: 1.0382x; 1.0123x over previous
//
#include <hip/hip_runtime.h>
#include <hip/hip_bf16.h>

typedef __hip_bfloat16 bf16;
typedef __attribute__((ext_vector_type(8))) short short8v;   // 8 bf16 (4 VGPR)
typedef __attribute__((ext_vector_type(4))) float float4v;   // MFMA acc

// ---------------- layouts ----------------
// Tile layouts (bf16, XOR-swizzled channel dim, batch=2048 in 32 blocks of 64):
//  t1T/h1T: [pix 196][cb 32][col 64][ch 64]   elem ((pix*32+cb)<<12) + col*64  + (ch ^ ((col&7)<<3))
//  t2T/p2T: [pos 25][cb 32][col 64][ch 128]   elem ((pos*32+cb)<<13) + col*128 + (ch ^ ((col&7)<<3))
//  t3T/p3T: [pos 4][cb 32][col 64][ch 256]    elem ((pos*32+cb)<<14) + col*256 + (ch ^ ((col&7)<<3))
// Weights (hi/lo split bf16, fp32-equivalent):
//  W2f [25][128 oc][64 ic] (ic swz by oc&7)  — fwd2 A     (+204800 lo)
//  W2u [25][64 ic][128 oc] (oc swz by ic&7)  — upd1 A     (hi only used)
//  W3m [9][256 oc][128 ic] (ic swz by oc&7)  — fwd3 A     (+294912 lo)
//  W3u [9][128 ic][256 oc] (oc swz by ic&7)  — upd2 A     (hi only used)
// e2T/e3T: masked error tiles (same layouts as t2T/t3T), scratch in d_out.
//   Computed in fwd2m/fwd3m epilogues (bit-exact vs separate pass).
// All MFMA LDS staging uses global_load_lds width-16 (linear lane*16 dest).
// EMPIRICAL OPERATING POINT (3 probes): loop MFMA kernels at 48KB LDS,
//   3 blocks/CU, grids >=800 or multi-round. Deviations (kernel merge,
//   >48KB tiles, grid 400 for upd2m) all regressed. fwd2m/upd1m: 2-cb
//   blocking (kept full rounds). fwd3m: och in [0,4). upd2m: 1-cb, grid 800.
// XCD-clustered 1-D decode (grids %8==0): cb clusters of 4 per XCD.
// fu3: w4s additive swizzle phys(k)=k+((k>>7)<<2), row 1056 (bank-conflict
//   fix; k0%128<=123 so paired +4 read stays in-block).
// First-iteration aliasing: t1==h1, t2==p2, t3==p3 bit-exactly.

__device__ __forceinline__ float b2f(bf16 v) { return __bfloat162float(v); }
__device__ __forceinline__ bf16  f2b(float v) { return __float2bfloat16(v); }
__device__ __forceinline__ float blo(unsigned u) { return __uint_as_float(u << 16); }
__device__ __forceinline__ float bhi(unsigned u) { return __uint_as_float(u & 0xffff0000u); }
__device__ __forceinline__ unsigned short fbits(float v) {
  union { bf16 b; unsigned short u; } c; c.b = f2b(v); return c.u;
}
__device__ __forceinline__ float ubf(unsigned short u) {
  return __uint_as_float(((unsigned)u) << 16);
}
// async global->LDS, 16B per lane. LDS dest must be wave-uniform base + lane*16.
__device__ __forceinline__ void gld16(const void* g, void* l) {
  __builtin_amdgcn_global_load_lds((const unsigned int*)g, (unsigned int*)l, 16, 0, 0);
}

// ---- weight prep ----
__global__ __launch_bounds__(256) void k_prep(
    const float* __restrict__ W1, const float* __restrict__ W2,
    const float* __restrict__ W3, float* __restrict__ W1t,
    short* __restrict__ W2f, short* __restrict__ W2u,
    short* __restrict__ W3m, short* __restrict__ W3u) {
  int i = blockIdx.x * 256 + threadIdx.x;
  if (i < 4800) {
    int oc = i / 75, k = i % 75;
    W1t[k * 64 + oc] = W1[i];
  }
  if (i < 204800) {
    int oc = i / 1600, k = i % 1600, ic = k / 25, tap = k % 25;
    float w = W2[i];
    unsigned short hi = fbits(w);
    unsigned short lo = fbits(w - ubf(hi));
    W2f[(tap * 128 + oc) * 64 + (ic ^ ((oc & 7) << 3))] = (short)hi;
    W2f[204800 + (tap * 128 + oc) * 64 + (ic ^ ((oc & 7) << 3))] = (short)lo;
    W2u[(tap * 64 + ic) * 128 + (oc ^ ((ic & 7) << 3))] = (short)hi;
  }
  if (i < 294912) {
    int oc = i / 1152, k = i % 1152, ic = k / 9, tap = k % 9;
    float w = W3[i];
    unsigned short hi = fbits(w);
    unsigned short lo = fbits(w - ubf(hi));
    W3m[(tap * 256 + oc) * 128 + (ic ^ ((oc & 7) << 3))] = (short)hi;
    W3m[294912 + (tap * 256 + oc) * 128 + (ic ^ ((oc & 7) << 3))] = (short)lo;
    W3u[(tap * 128 + ic) * 256 + (oc ^ ((ic & 7) << 3))] = (short)hi;
  }
}

// ---- conv1 (LDS-staged, 512 threads): h1T = relu(conv1(x)) ----
// block=(bt,oy), oy in [0,14). Wave w8: oc-group w8&3, h-half w8>>2.
__global__ __launch_bounds__(512, 1) void k_conv1s(
    const float* __restrict__ x, const float* __restrict__ W1t,
    const float* __restrict__ b1, bf16* __restrict__ h1T) {
  __shared__ float xs[480 * 66];  // [f 480 = ic*160+ky*32+x][col 64 (+2 pad)]
  __shared__ float ws[4800];      // [tap 75][oc 64]
  int bt = blockIdx.x, oy = blockIdx.y;
  int tid = threadIdx.x, lane = tid & 63, w8 = tid >> 6;
  int wv = w8 & 3, h = w8 >> 2;
  for (int i = tid; i < 4800; i += 512) ws[i] = W1t[i];
#pragma unroll
  for (int r = 0; r < 15; ++r) {
    int idx = r * 512 + tid;
    int col = idx / 120, q = idx % 120;
    int ic = q / 40, rem = q % 40;
    float4 v = *(const float4*)(x + (size_t)(bt * 64 + col) * 3072 +
                                ic * 1024 + oy * 64 + rem * 4);
    float* d = xs + (ic * 160 + rem * 4) * 66 + col;
    d[0] = v.x;
    d[66] = v.y;
    d[132] = v.z;
    d[198] = v.w;
  }
  __syncthreads();
  int oc0 = wv * 16;
  float acc[7][16];
#pragma unroll
  for (int o = 0; o < 7; ++o)
#pragma unroll
    for (int j = 0; j < 16; ++j) acc[o][j] = b1[oc0 + j];
  for (int ic = 0; ic < 3; ++ic)
    for (int ky = 0; ky < 5; ++ky) {
#pragma unroll
      for (int kx = 0; kx < 5; ++kx) {
        const float* wp = ws + ((ic * 25 + ky * 5 + kx) << 6) + oc0;
        float4 w0 = *(const float4*)(wp);
        float4 w1 = *(const float4*)(wp + 4);
        float4 w2 = *(const float4*)(wp + 8);
        float4 w3 = *(const float4*)(wp + 12);
        const float* xr = xs + (ic * 160 + ky * 32 + kx) * 66 + lane;
        float xv[7];
#pragma unroll
        for (int o = 0; o < 7; ++o) xv[o] = xr[(2 * (h * 7 + o)) * 66];
#pragma unroll
        for (int o = 0; o < 7; ++o) {
          float e = xv[o];
          acc[o][0] += e * w0.x;  acc[o][1] += e * w0.y;
          acc[o][2] += e * w0.z;  acc[o][3] += e * w0.w;
          acc[o][4] += e * w1.x;  acc[o][5] += e * w1.y;
          acc[o][6] += e * w1.z;  acc[o][7] += e * w1.w;
          acc[o][8] += e * w2.x;  acc[o][9] += e * w2.y;
          acc[o][10] += e * w2.z; acc[o][11] += e * w2.w;
          acc[o][12] += e * w3.x; acc[o][13] += e * w3.y;
          acc[o][14] += e * w3.z; acc[o][15] += e * w3.w;
        }
      }
    }
#pragma unroll
  for (int o = 0; o < 7; ++o) {
    int pix = oy * 14 + h * 7 + o;
    size_t tbase = ((size_t)(pix * 32 + bt)) << 12;
#pragma unroll
    for (int q = 0; q < 4; ++q) {
      ushort4 pk;
      pk.x = fbits(fmaxf(acc[o][q * 4 + 0], 0.f));
      pk.y = fbits(fmaxf(acc[o][q * 4 + 1], 0.f));
      pk.z = fbits(fmaxf(acc[o][q * 4 + 2], 0.f));
      pk.w = fbits(fmaxf(acc[o][q * 4 + 3], 0.f));
      int ocr = oc0 + q * 4;
      size_t off = tbase + lane * 64 + (ocr ^ ((lane & 7) << 3));
      *(ushort4*)(h1T + off) = pk;
    }
  }
}

// ---- fwd2 (MFMA, 2-cb): p2T = relu(conv2(in1)); fused e2T ----
// grid 400 (1-D): xcd=bid&7, j=bid>>3 (0..49), cbp=xcd*2+(j&1), pos=j>>1
__global__ __launch_bounds__(256) void k_fwd2m(
    const bf16* __restrict__ in1, const short* __restrict__ W2f,
    const float* __restrict__ b2, bf16* __restrict__ p2T,
    const bf16* __restrict__ t2e, bf16* __restrict__ e2T, int einit) {
  __shared__ __align__(16) short As0[8192];     // hi [128 oc][64 ic]
  __shared__ __align__(16) short As1[8192];     // lo
  __shared__ __align__(16) short Bs[2][4096];   // [cb][64 col][64 ic]
  int bid = blockIdx.x;
  int j = bid >> 3;
  int cbp = (bid & 7) * 2 + (j & 1), pos = j >> 1;
  int cb0 = cbp * 2;
  int tid = threadIdx.x, lane = tid & 63, wv = tid >> 6;
  int oy = pos / 5, ox = pos % 5;
  float4v acc[2][2][4];
#pragma unroll
  for (int c = 0; c < 2; ++c)
#pragma unroll
    for (int m = 0; m < 2; ++m)
#pragma unroll
      for (int n = 0; n < 4; ++n) acc[c][m][n] = (float4v){0.f, 0.f, 0.f, 0.f};

  for (int tap = 0; tap < 25; ++tap) {
    int ky = tap / 5, kx = tap % 5;
    int ipix = (2 * oy + ky) * 14 + (2 * ox + kx);
    __syncthreads();
    {
      const uint4* bs0 = (const uint4*)(in1 + (((size_t)(ipix * 32 + cb0)) << 12));
      const uint4* bs1 = (const uint4*)(in1 + (((size_t)(ipix * 32 + cb0 + 1)) << 12));
      uint4* bd = (uint4*)Bs;
      gld16(&bs0[tid], &bd[tid]);
      gld16(&bs0[tid + 256], &bd[tid + 256]);
      gld16(&bs1[tid], &bd[tid + 512]);
      gld16(&bs1[tid + 256], &bd[tid + 768]);
      const uint4* ah = (const uint4*)(W2f + tap * 8192);
      const uint4* al = (const uint4*)(W2f + 204800 + tap * 8192);
      uint4* dh = (uint4*)As0;
      uint4* dl = (uint4*)As1;
#pragma unroll
      for (int p = 0; p < 4; ++p) {
        gld16(&ah[tid + p * 256], &dh[tid + p * 256]);
        gld16(&al[tid + p * 256], &dl[tid + p * 256]);
      }
    }
    __syncthreads();
#pragma unroll
    for (int ks = 0; ks < 2; ++ks) {
      int ic0 = ks * 32 + ((lane >> 4) << 3);
      short8v bfr[2][4];
#pragma unroll
      for (int c = 0; c < 2; ++c)
#pragma unroll
        for (int n = 0; n < 4; ++n) {
          int colv = n * 16 + (lane & 15);
          bfr[c][n] = *(const short8v*)(&Bs[c][0] + colv * 64 + (ic0 ^ ((colv & 7) << 3)));
        }
#pragma unroll
      for (int m = 0; m < 2; ++m) {
        int row = wv * 32 + m * 16 + (lane & 15);
        int aoff = row * 64 + (ic0 ^ ((row & 7) << 3));
        short8v ah = *(const short8v*)(As0 + aoff);
        short8v al = *(const short8v*)(As1 + aoff);
#pragma unroll
        for (int c = 0; c < 2; ++c)
#pragma unroll
          for (int n = 0; n < 4; ++n) {
            acc[c][m][n] = __builtin_amdgcn_mfma_f32_16x16x32_bf16(ah, bfr[c][n], acc[c][m][n], 0, 0, 0);
            acc[c][m][n] = __builtin_amdgcn_mfma_f32_16x16x32_bf16(al, bfr[c][n], acc[c][m][n], 0, 0, 0);
          }
      }
    }
  }
#pragma unroll
  for (int c = 0; c < 2; ++c) {
    size_t tb2 = ((size_t)(pos * 32 + cb0 + c)) << 13;
#pragma unroll
    for (int m = 0; m < 2; ++m) {
      int ocb = wv * 32 + m * 16 + ((lane >> 4) << 2);
      float4 bv = *(const float4*)(b2 + ocb);
#pragma unroll
      for (int n = 0; n < 4; ++n) {
        int colv = n * 16 + (lane & 15);
        ushort4 pk;
        pk.x = fbits(fmaxf(acc[c][m][n][0] + bv.x, 0.f));
        pk.y = fbits(fmaxf(acc[c][m][n][1] + bv.y, 0.f));
        pk.z = fbits(fmaxf(acc[c][m][n][2] + bv.z, 0.f));
        pk.w = fbits(fmaxf(acc[c][m][n][3] + bv.w, 0.f));
        size_t off = tb2 + colv * 128 + (ocb ^ ((colv & 7) << 3));
        *(ushort4*)(p2T + off) = pk;
        if (einit) {
          ushort4 z = {0, 0, 0, 0};
          *(ushort4*)(e2T + off) = z;
        } else {
          ushort4 tv = *(const ushort4*)(t2e + off);
          ushort4 ev;
          float p0, t0;
          p0 = ubf(pk.x); t0 = ubf(tv.x); ev.x = fbits(p0 > 0.f ? t0 - p0 : 0.f);
          p0 = ubf(pk.y); t0 = ubf(tv.y); ev.y = fbits(p0 > 0.f ? t0 - p0 : 0.f);
          p0 = ubf(pk.z); t0 = ubf(tv.z); ev.z = fbits(p0 > 0.f ? t0 - p0 : 0.f);
          p0 = ubf(pk.w); t0 = ubf(tv.w); ev.w = fbits(p0 > 0.f ? t0 - p0 : 0.f);
          *(ushort4*)(e2T + off) = ev;
        }
      }
    }
  }
}

// ---- upd1 (MFMA, hi-only, 2-cb): g1 = conv2^T(e2T); t1w = upd(t1r) ----
// grid 3136 (1-D): xcd=bid&7, j=bid>>3 (0..391), cbp=xcd*2+(j&1), pix=j>>1
__global__ __launch_bounds__(256) void k_upd1m(
    const bf16* __restrict__ e2T, const short* __restrict__ W2u,
    const bf16* __restrict__ h1T, const bf16* __restrict__ t1r,
    bf16* __restrict__ t1w) {
  __shared__ __align__(16) short As0[8192];    // hi [64 ic][128 oc]
  __shared__ __align__(16) short Es[2][8192];  // [cb][64 col][128 oc]
  int bid = blockIdx.x;
  int j = bid >> 3;
  int cbp = (bid & 7) * 2 + (j & 1), pix = j >> 1;
  int cb0 = cbp * 2;
  int tid = threadIdx.x, lane = tid & 63, wv = tid >> 6;
  int iy = pix / 14, ix = pix % 14;
  float4v acc[2][4];
#pragma unroll
  for (int c = 0; c < 2; ++c)
#pragma unroll
    for (int n = 0; n < 4; ++n) acc[c][n] = (float4v){0.f, 0.f, 0.f, 0.f};

  for (int ky = iy & 1; ky <= 4; ky += 2) {
    int oy = (iy - ky) >> 1;
    if (oy < 0 || oy > 4) continue;
    for (int kx = ix & 1; kx <= 4; kx += 2) {
      int ox = (ix - kx) >> 1;
      if (ox < 0 || ox > 4) continue;
      int erow = oy * 5 + ox, tap = ky * 5 + kx;
      __syncthreads();
      {
        const uint4* es0 = (const uint4*)(e2T + (((size_t)(erow * 32 + cb0)) << 13));
        const uint4* es1 = (const uint4*)(e2T + (((size_t)(erow * 32 + cb0 + 1)) << 13));
        uint4* ed = (uint4*)Es;
        const uint4* ah = (const uint4*)(W2u + tap * 8192);
        uint4* dh = (uint4*)As0;
#pragma unroll
        for (int p = 0; p < 4; ++p) {
          gld16(&es0[tid + p * 256], &ed[tid + p * 256]);
          gld16(&es1[tid + p * 256], &ed[tid + p * 256 + 1024]);
          gld16(&ah[tid + p * 256], &dh[tid + p * 256]);
        }
      }
      __syncthreads();
#pragma unroll
      for (int ks = 0; ks < 4; ++ks) {
        int oc0 = ks * 32 + ((lane >> 4) << 3);
        int row = wv * 16 + (lane & 15);
        int aoff = row * 128 + (oc0 ^ ((row & 7) << 3));
        short8v ah = *(const short8v*)(As0 + aoff);
#pragma unroll
        for (int c = 0; c < 2; ++c)
#pragma unroll
          for (int n = 0; n < 4; ++n) {
            int colv = n * 16 + (lane & 15);
            short8v ef = *(const short8v*)(&Es[c][0] + colv * 128 + (oc0 ^ ((colv & 7) << 3)));
            acc[c][n] = __builtin_amdgcn_mfma_f32_16x16x32_bf16(ah, ef, acc[c][n], 0, 0, 0);
          }
      }
    }
  }
  int icb = wv * 16 + ((lane >> 4) << 2);
#pragma unroll
  for (int c = 0; c < 2; ++c) {
    size_t tb1 = ((size_t)(pix * 32 + cb0 + c)) << 12;
#pragma unroll
    for (int n = 0; n < 4; ++n) {
      int colv = n * 16 + (lane & 15);
      size_t off = tb1 + colv * 64 + (icb ^ ((colv & 7) << 3));
      ushort4 tv = *(const ushort4*)(t1r + off);
      ushort4 hv = *(const ushort4*)(h1T + off);
      ushort4 rp;
      float t0, h0;
      t0 = ubf(tv.x); h0 = ubf(hv.x);
      rp.x = fbits(t0 - 0.07f * (t0 - h0) + 0.07f * acc[c][n][0]);
      t0 = ubf(tv.y); h0 = ubf(hv.y);
      rp.y = fbits(t0 - 0.07f * (t0 - h0) + 0.07f * acc[c][n][1]);
      t0 = ubf(tv.z); h0 = ubf(hv.z);
      rp.z = fbits(t0 - 0.07f * (t0 - h0) + 0.07f * acc[c][n][2]);
      t0 = ubf(tv.w); h0 = ubf(hv.w);
      rp.w = fbits(t0 - 0.07f * (t0 - h0) + 0.07f * acc[c][n][3]);
      *(ushort4*)(t1w + off) = rp;
    }
  }
}

// ---- fwd3 (MFMA): p3T = relu(conv3(in2)); fused e3T = mask(p3)*(t3e-p3) ----
// grid 512 (1-D): xcd=bid&7, j=bid>>3, cb=xcd*4+(j&3), r=j>>2, pos=r&3, och=r>>2
__global__ __launch_bounds__(256) void k_fwd3m(
    const bf16* __restrict__ in2, const short* __restrict__ W3m,
    const float* __restrict__ b3, bf16* __restrict__ p3T,
    const bf16* __restrict__ t3e, bf16* __restrict__ e3T, int einit) {
  __shared__ __align__(16) short As0[8192];  // hi [64 oc][128 ic]
  __shared__ __align__(16) short As1[8192];  // lo
  __shared__ __align__(16) short Bs[8192];   // [64 col][128 ic]
  int bid = blockIdx.x;
  int j = bid >> 3;
  int cb = (bid & 7) * 4 + (j & 3);
  int r = j >> 2;
  int pos = r & 3, och = r >> 2;
  int tid = threadIdx.x, lane = tid & 63, wv = tid >> 6;
  int oy = pos >> 1, ox = pos & 1;
  float4v acc[4];
#pragma unroll
  for (int n = 0; n < 4; ++n) acc[n] = (float4v){0.f, 0.f, 0.f, 0.f};

  for (int tap = 0; tap < 9; ++tap) {
    int ky = tap / 3, kx = tap % 3;
    int irow = (2 * oy + ky) * 5 + (2 * ox + kx);
    __syncthreads();
    {
      const uint4* bs = (const uint4*)(in2 + (((size_t)(irow * 32 + cb)) << 13));
      uint4* bd = (uint4*)Bs;
#pragma unroll
      for (int p = 0; p < 4; ++p) gld16(&bs[tid + p * 256], &bd[tid + p * 256]);
      const uint4* ah = (const uint4*)(W3m + ((size_t)tap * 256 + och * 64) * 128);
      const uint4* al = (const uint4*)(W3m + 294912 + ((size_t)tap * 256 + och * 64) * 128);
      uint4* dh = (uint4*)As0;
      uint4* dl = (uint4*)As1;
#pragma unroll
      for (int p = 0; p < 4; ++p) {
        gld16(&ah[tid + p * 256], &dh[tid + p * 256]);
        gld16(&al[tid + p * 256], &dl[tid + p * 256]);
      }
    }
    __syncthreads();
#pragma unroll
    for (int ks = 0; ks < 4; ++ks) {
      int ic0 = ks * 32 + ((lane >> 4) << 3);
      short8v bfr[4];
#pragma unroll
      for (int n = 0; n < 4; ++n) {
        int colv = n * 16 + (lane & 15);
        bfr[n] = *(const short8v*)(Bs + colv * 128 + (ic0 ^ ((colv & 7) << 3)));
      }
      int row = wv * 16 + (lane & 15);
      int aoff = row * 128 + (ic0 ^ ((row & 7) << 3));
      short8v ah = *(const short8v*)(As0 + aoff);
      short8v al = *(const short8v*)(As1 + aoff);
#pragma unroll
      for (int n = 0; n < 4; ++n) {
        acc[n] = __builtin_amdgcn_mfma_f32_16x16x32_bf16(ah, bfr[n], acc[n], 0, 0, 0);
        acc[n] = __builtin_amdgcn_mfma_f32_16x16x32_bf16(al, bfr[n], acc[n], 0, 0, 0);
      }
    }
  }
  size_t tb3 = ((size_t)(pos * 32 + cb)) << 14;
  int ocg = och * 64 + wv * 16 + ((lane >> 4) << 2);
  float4 bv = *(const float4*)(b3 + ocg);
#pragma unroll
  for (int n = 0; n < 4; ++n) {
    int colv = n * 16 + (lane & 15);
    ushort4 pk;
    pk.x = fbits(fmaxf(acc[n][0] + bv.x, 0.f));
    pk.y = fbits(fmaxf(acc[n][1] + bv.y, 0.f));
    pk.z = fbits(fmaxf(acc[n][2] + bv.z, 0.f));
    pk.w = fbits(fmaxf(acc[n][3] + bv.w, 0.f));
    size_t off = tb3 + colv * 256 + (ocg ^ ((colv & 7) << 3));
    *(ushort4*)(p3T + off) = pk;
    if (einit) {
      ushort4 z = {0, 0, 0, 0};
      *(ushort4*)(e3T + off) = z;
    } else {
      ushort4 tv = *(const ushort4*)(t3e + off);
      ushort4 ev;
      float p0, t0;
      p0 = ubf(pk.x); t0 = ubf(tv.x); ev.x = fbits(p0 > 0.f ? t0 - p0 : 0.f);
      p0 = ubf(pk.y); t0 = ubf(tv.y); ev.y = fbits(p0 > 0.f ? t0 - p0 : 0.f);
      p0 = ubf(pk.z); t0 = ubf(tv.z); ev.z = fbits(p0 > 0.f ? t0 - p0 : 0.f);
      p0 = ubf(pk.w); t0 = ubf(tv.w); ev.w = fbits(p0 > 0.f ? t0 - p0 : 0.f);
      *(ushort4*)(e3T + off) = ev;
    }
  }
}

// ---- upd2 (MFMA, hi-only): g2 = conv3^T(e3T); t2w = upd(t2r) ----
// grid 800 (1-D): xcd=bid&7, j=bid>>3, cb=xcd*4+(j&3), pix=j>>2
__global__ __launch_bounds__(256) void k_upd2m(
    const bf16* __restrict__ e3T, const bf16* __restrict__ p2T,
    const short* __restrict__ W3u, const bf16* __restrict__ t2r,
    bf16* __restrict__ t2w) {
  __shared__ __align__(16) short Es[8192];    // [64 col][128 oc_local]
  __shared__ __align__(16) short As0[16384];  // hi [128 ic][128 oc_local]
  int bid = blockIdx.x;
  int j = bid >> 3;
  int cb = (bid & 7) * 4 + (j & 3), pix = j >> 2;
  int tid = threadIdx.x, lane = tid & 63, wv = tid >> 6;
  int iy = pix / 5, ix = pix % 5;
  float4v acc[2][4];
#pragma unroll
  for (int m = 0; m < 2; ++m)
#pragma unroll
    for (int n = 0; n < 4; ++n) acc[m][n] = (float4v){0.f, 0.f, 0.f, 0.f};

  for (int ky = iy & 1; ky <= 2; ky += 2) {
    int oy = (iy - ky) >> 1;
    if (oy < 0 || oy > 1) continue;
    for (int kx = ix & 1; kx <= 2; kx += 2) {
      int ox = (ix - kx) >> 1;
      if (ox < 0 || ox > 1) continue;
      int erow = oy * 2 + ox, tap = ky * 3 + kx;
      for (int occ = 0; occ < 2; ++occ) {
        __syncthreads();
        {
          size_t tb = ((size_t)(erow * 32 + cb)) << 14;
          uint4* ed = (uint4*)Es;
#pragma unroll
          for (int p = 0; p < 4; ++p) {
            int fi = tid + p * 256;
            int colr = fi >> 4, q = fi & 15;
            size_t g = tb + colr * 256 + occ * 128 + q * 8;
            gld16(e3T + g, &ed[fi]);
          }
          uint4* dh = (uint4*)As0;
#pragma unroll
          for (int p = 0; p < 8; ++p) {
            int fi = tid + p * 256;
            int icr = fi >> 4, q = fi & 15;
            size_t srcoff = ((size_t)(tap * 128 + icr)) * 256 + occ * 128 + q * 8;
            gld16(W3u + srcoff, &dh[fi]);
          }
        }
        __syncthreads();
#pragma unroll
        for (int ks = 0; ks < 4; ++ks) {
          int oc0 = ks * 32 + ((lane >> 4) << 3);
          short8v efr[4];
#pragma unroll
          for (int n = 0; n < 4; ++n) {
            int colv = n * 16 + (lane & 15);
            efr[n] = *(const short8v*)(Es + colv * 128 + (oc0 ^ ((colv & 7) << 3)));
          }
#pragma unroll
          for (int m = 0; m < 2; ++m) {
            int icr = wv * 32 + m * 16 + (lane & 15);
            int aoff = icr * 128 + (oc0 ^ ((icr & 7) << 3));
            short8v ah = *(const short8v*)(As0 + aoff);
#pragma unroll
            for (int n = 0; n < 4; ++n) {
              acc[m][n] = __builtin_amdgcn_mfma_f32_16x16x32_bf16(ah, efr[n], acc[m][n], 0, 0, 0);
            }
          }
        }
      }
    }
  }
  size_t tb2 = ((size_t)(pix * 32 + cb)) << 13;
#pragma unroll
  for (int m = 0; m < 2; ++m) {
    int icr = wv * 32 + m * 16 + ((lane >> 4) << 2);
#pragma unroll
    for (int n = 0; n < 4; ++n) {
      int colv = n * 16 + (lane & 15);
      size_t off = tb2 + colv * 128 + (icr ^ ((colv & 7) << 3));
      ushort4 tv = *(const ushort4*)(t2r + off);
      ushort4 pv = *(const ushort4*)(p2T + off);
      ushort4 rp;
      float t0, p0;
      t0 = ubf(tv.x); p0 = ubf(pv.x);
      rp.x = fbits(t0 - 0.07f * (t0 - p0) + 0.07f * acc[m][n][0]);
      t0 = ubf(tv.y); p0 = ubf(pv.y);
      rp.y = fbits(t0 - 0.07f * (t0 - p0) + 0.07f * acc[m][n][1]);
      t0 = ubf(tv.z); p0 = ubf(pv.z);
      rp.z = fbits(t0 - 0.07f * (t0 - p0) + 0.07f * acc[m][n][2]);
      t0 = ubf(tv.w); p0 = ubf(pv.w);
      rp.w = fbits(t0 - 0.07f * (t0 - p0) + 0.07f * acc[m][n][3]);
      *(ushort4*)(t2w + off) = rp;
    }
  }
}

// ---- fu3: p4 = t3r @ W4^T + b4 (all-lane butterfly); softmax; e4;
//      g3 = e4 @ W4; t3w = upd(t3r).
//      w4s bank-conflict-free: phys(k) = k + ((k>>7)<<2), row stride 1056. ----
__global__ __launch_bounds__(256) void k_fu3(
    const float* __restrict__ gt, const float* __restrict__ W4,
    const float* __restrict__ b4, const bf16* __restrict__ p3T,
    const bf16* __restrict__ t3r, bf16* __restrict__ t3w) {
  __shared__ __align__(16) float w4s[10560];  // 10 rows x 1056 (swizzled)
  int tid = threadIdx.x;
  for (int i = tid; i < 10240; i += 256) {
    int o = i >> 10, k = i & 1023;
    w4s[o * 1056 + k + ((k >> 7) << 2)] = W4[i];
  }
  __syncthreads();
  int c = blockIdx.x * 8 + (tid >> 5);
  int cb = c >> 6, colL = c & 63, subk = tid & 31;
  int pos = subk & 3, ch0 = (subk >> 2) * 32;
  int xc = (colL & 7) << 3;
  size_t boff = (((size_t)(pos * 32 + cb)) << 14) + colL * 256 + ch0;
  const bf16* trd = t3r + boff;
  const bf16* pb = p3T + boff;
  uint4 tq[4];
#pragma unroll
  for (int q = 0; q < 4; ++q) tq[q] = *(const uint4*)(trd + q * 8);
  float acc[10] = {};
#pragma unroll
  for (int q = 0; q < 4; ++q) {
    unsigned wds[4] = {tq[q].x, tq[q].y, tq[q].z, tq[q].w};
    int chb = (ch0 + q * 8) ^ xc;
#pragma unroll
    for (int h = 0; h < 4; ++h) {
      float v0 = blo(wds[h]), v1 = bhi(wds[h]);
      int k0 = (chb + 2 * h) * 4 + pos;
      int ks = k0 + ((k0 >> 7) << 2);  // k0%128<=123 so +4 stays in-block
#pragma unroll
      for (int o = 0; o < 10; ++o)
        acc[o] += v0 * w4s[o * 1056 + ks] + v1 * w4s[o * 1056 + ks + 4];
    }
  }
#pragma unroll
  for (int off = 16; off > 0; off >>= 1)
#pragma unroll
    for (int o = 0; o < 10; ++o) acc[o] += __shfl_xor(acc[o], off, 32);
  float pv[10], m = -1e30f;
#pragma unroll
  for (int o = 0; o < 10; ++o) {
    pv[o] = acc[o] + b4[o];
    m = fmaxf(m, pv[o]);
  }
  float s = 0.f;
#pragma unroll
  for (int o = 0; o < 10; ++o) {
    pv[o] = __expf(pv[o] - m);
    s += pv[o];
  }
  float inv = 1.f / s;
  float e4[10];
#pragma unroll
  for (int o = 0; o < 10; ++o)
    e4[o] = (gt[(size_t)c * 10 + o] - pv[o] * inv) * 0.5f;
  bf16* tb = t3w + boff;
#pragma unroll
  for (int q = 0; q < 4; ++q) {
    uint4 pq = *(const uint4*)(pb + q * 8);
    unsigned tw[4] = {tq[q].x, tq[q].y, tq[q].z, tq[q].w};
    unsigned pw[4] = {pq.x, pq.y, pq.z, pq.w};
    int chb = (ch0 + q * 8) ^ xc;
    unsigned ro[4];
#pragma unroll
    for (int h = 0; h < 4; ++h) {
      int k0 = (chb + 2 * h) * 4 + pos;
      int ks = k0 + ((k0 >> 7) << 2);
      float g0 = 0.f, g1 = 0.f;
#pragma unroll
      for (int o = 0; o < 10; ++o) {
        g0 += e4[o] * w4s[o * 1056 + ks];
        g1 += e4[o] * w4s[o * 1056 + ks + 4];
      }
      float t0 = blo(tw[h]), p0 = blo(pw[h]);
      float t1 = bhi(tw[h]), p1 = bhi(pw[h]);
      float r0 = t0 - 0.07f * (t0 - p0) + 0.07f * g0;
      float r1 = t1 - 0.07f * (t1 - p1) + 0.07f * g1;
      ro[h] = (unsigned)fbits(r0) | ((unsigned)fbits(r1) << 16);
    }
    uint4 rv = {ro[0], ro[1], ro[2], ro[3]};
    *(uint4*)(tb + q * 8) = rv;
  }
}

// ---- k_tr1: t1 section gather (contiguous slab reads, LDS rotate) ----
__global__ __launch_bounds__(256) void k_tr1(
    const bf16* __restrict__ t1T, float* __restrict__ out) {
  __shared__ short lds[2 * 64 * 224];
  int cb = blockIdx.x, c0 = blockIdx.y * 2;
  int tid = threadIdx.x;
  for (int i = tid; i < 3136; i += 256) {
    int pix = i >> 4, q = i & 15;
    int colL = q >> 3, chb = (q & 7) << 3;
    int col = c0 + colL;
    uint4 v = *(const uint4*)(t1T + (((size_t)(pix * 32 + cb)) << 12) + col * 64 + chb);
    int icb = chb ^ ((col & 7) << 3);
    int posX = pix ^ (((icb >> 3) & 7) << 2);
    short* d = lds + (colL * 64 + icb) * 224 + posX;
    const short* vs = (const short*)&v;
#pragma unroll
    for (int j = 0; j < 8; ++j) d[j * 224] = vs[j];
  }
  __syncthreads();
  for (int i = tid; i < 6272; i += 256) {
    int colL = i / 3136, m = i % 3136;
    int ic = m / 49, pp = m % 49;
    int posX = (pp * 4) ^ (((ic >> 3) & 7) << 2);
    const short* s = lds + (colL * 64 + ic) * 224 + posX;
    float4 o;
    o.x = ubf((unsigned short)s[0]);
    o.y = ubf((unsigned short)s[1]);
    o.z = ubf((unsigned short)s[2]);
    o.w = ubf((unsigned short)s[3]);
    *(float4*)(out + ((size_t)(cb * 64 + c0 + colL)) * 16768 + m * 4) = o;
  }
}

// ---- k_tr2: t2 section gather ----
__global__ __launch_bounds__(256) void k_tr2(
    const bf16* __restrict__ t2T, float* __restrict__ out) {
  __shared__ short lds[4 * 128 * 32];
  int cb = blockIdx.x, c0 = blockIdx.y * 4;
  int tid = threadIdx.x;
  for (int i = tid; i < 1600; i += 256) {
    int pos = i >> 6, q = i & 63;
    int colL = q >> 4, chb = (q & 15) << 3;
    int col = c0 + colL;
    uint4 v = *(const uint4*)(t2T + (((size_t)(pos * 32 + cb)) << 13) + col * 128 + chb);
    int ocb = chb ^ ((col & 7) << 3);
    int posX = pos ^ (((ocb >> 3) & 7) << 2);
    short* d = lds + (colL * 128 + ocb) * 32 + posX;
    const short* vs = (const short*)&v;
#pragma unroll
    for (int j = 0; j < 8; ++j) d[j * 32] = vs[j];
  }
  __syncthreads();
  for (int i = tid; i < 3200; i += 256) {
    int colL = i / 800, m = i % 800;
    int f0 = m * 4;
    float4 o;
    float* po = &o.x;
#pragma unroll
    for (int t = 0; t < 4; ++t) {
      int f = f0 + t;
      int oc = f / 25, pos = f % 25;
      int posX = pos ^ (((oc >> 3) & 7) << 2);
      po[t] = ubf((unsigned short)lds[(colL * 128 + oc) * 32 + posX]);
    }
    *(float4*)(out + ((size_t)(cb * 64 + c0 + colL)) * 16768 + 12544 + f0) = o;
  }
}

// ---- k_tr3: t3 section gather, register transpose ----
__global__ __launch_bounds__(256) void k_tr3(
    const bf16* __restrict__ t3T, float* __restrict__ out) {
  int tid = threadIdx.x;
  int sample = blockIdx.x * 8 + (tid >> 5);
  int cb = sample >> 6, col = sample & 63;
  int chb = (tid & 31) << 3;
  int icb = chb ^ ((col & 7) << 3);
  uint4 v[4];
#pragma unroll
  for (int pos = 0; pos < 4; ++pos)
    v[pos] = *(const uint4*)(t3T + (((size_t)(pos * 32 + cb)) << 14) + col * 256 + chb);
  const unsigned short* s0 = (const unsigned short*)&v[0];
  const unsigned short* s1 = (const unsigned short*)&v[1];
  const unsigned short* s2 = (const unsigned short*)&v[2];
  const unsigned short* s3 = (const unsigned short*)&v[3];
  float* ob = out + (size_t)sample * 16768 + 15744 + icb * 4;
#pragma unroll
  for (int j = 0; j < 8; ++j) {
    float4 o;
    o.x = ubf(s0[j]);
    o.y = ubf(s1[j]);
    o.z = ubf(s2[j]);
    o.w = ubf(s3[j]);
    *(float4*)(ob + j * 4) = o;
  }
}

extern "C" void kernel_launch(void* const* d_in, const int* in_sizes, int n_in,
                              void* d_out, int out_size, void* d_ws,
                              size_t ws_size, hipStream_t stream) {
  const float* x  = (const float*)d_in[0];
  const float* gt = (const float*)d_in[1];
  const float* W1 = (const float*)d_in[2];
  const float* b1 = (const float*)d_in[3];
  const float* W2 = (const float*)d_in[4];
  const float* b2 = (const float*)d_in[5];
  const float* W3 = (const float*)d_in[6];
  const float* b3 = (const float*)d_in[7];
  const float* W4 = (const float*)d_in[8];
  const float* b4 = (const float*)d_in[9];
  float* out = (float*)d_out;

  bf16* h1T = (bf16*)d_ws;
  bf16* t1T = h1T + 25690112ull;
  bf16* t2T = t1T + 25690112ull;
  bf16* p2T = t2T + 6553600ull;
  bf16* t3T = p2T + 6553600ull;
  bf16* p3T = t3T + 2097152ull;
  float* p4f = (float*)(p3T + 2097152ull);  // unused (kept for layout)
  float* W1t = p4f + 20480;
  short* W3m = (short*)(W1t + 4800);
  short* W3u = W3m + 589824;
  short* W2f = W3u + 589824;
  short* W2u = W2f + 409600;
  // e2T/e3T (13.1 + 4.2 MB bf16) live in d_out (134 MB), dead until k_tr*.
  bf16* e2T = (bf16*)out;
  bf16* e3T = e2T + 6553600ull;

  dim3 blk(256);

  k_prep<<<1152, blk, 0, stream>>>(W1, W2, W3, W1t, W2f, W2u, W3m, W3u);
  k_conv1s<<<dim3(32, 14), dim3(512), 0, stream>>>(x, W1t, b1, h1T);
  k_fwd2m<<<400, blk, 0, stream>>>(h1T, W2f, b2, p2T, p2T, e2T, 1);
  k_fwd3m<<<512, blk, 0, stream>>>(p2T, W3m, b3, p3T, p3T, e3T, 1);

  for (int it = 0; it < 25; ++it) {
    const bf16* t1r = (it == 0) ? h1T : t1T;
    const bf16* t2r = (it == 0) ? p2T : t2T;
    const bf16* t3r = (it == 0) ? p3T : t3T;
    k_upd1m<<<3136, blk, 0, stream>>>(e2T, W2u, h1T, t1r, t1T);
    k_upd2m<<<800, blk, 0, stream>>>(e3T, p2T, W3u, t2r, t2T);
    k_fu3<<<256, blk, 0, stream>>>(gt, W4, b4, p3T, t3r, t3T);
    if (it < 24) {
      k_fwd2m<<<400, blk, 0, stream>>>(t1T, W2f, b2, p2T, t2T, e2T, 0);
      k_fwd3m<<<512, blk, 0, stream>>>(t2T, W3m, b3, p3T, t3T, e3T, 0);
    }
  }
  k_tr1<<<dim3(32, 32), blk, 0, stream>>>(t1T, out);
  k_tr2<<<dim3(32, 16), blk, 0, stream>>>(t2T, out);
  k_tr3<<<256, blk, 0, stream>>>(t3T, out);
}

// Round 15
// 3146.195 us; speedup vs baseline: 1.1165x; 1.0754x over previous
//
#include <hip/hip_runtime.h>
#include <hip/hip_bf16.h>

typedef __hip_bfloat16 bf16;
typedef __attribute__((ext_vector_type(8))) short short8v;   // 8 bf16 (4 VGPR)
typedef __attribute__((ext_vector_type(4))) float float4v;   // MFMA acc

// ---------------- layouts ----------------
// Tile layouts (bf16, XOR-swizzled channel dim, batch=2048 in 32 blocks of 64):
//  t1T/h1T: [pix 196][cb 32][col 64][ch 64]   elem ((pix*32+cb)<<12) + col*64  + (ch ^ ((col&7)<<3))
//  t2T/p2T: [pos 25][cb 32][col 64][ch 128]   elem ((pos*32+cb)<<13) + col*128 + (ch ^ ((col&7)<<3))
//  t3T/p3T: [pos 4][cb 32][col 64][ch 256]    elem ((pos*32+cb)<<14) + col*256 + (ch ^ ((col&7)<<3))
// Weights (bf16; hi/lo split retained in ws layout, lo now unused):
//  W2f [25][128 oc][64 ic] (ic swz by oc&7)  — fwd2 A (hi only used)
//  W2u [25][64 ic][128 oc] (oc swz by ic&7)  — upd1 A (hi only used)
//  W3m [9][256 oc][128 ic] (ic swz by oc&7)  — fwd3 A (hi only used)
//  W3u [9][128 ic][256 oc] (oc swz by ic&7)  — upd2 A (hi only used)
// e2T/e3T: masked error tiles (same layouts as t2T/t3T), scratch in d_out.
//   Computed in fwd2m/fwd3m epilogues.
// All MFMA LDS staging uses global_load_lds width-16 (linear lane*16 dest).
// OPERATING POINT (3 probes): loop MFMA kernels <=48KB LDS, >=3 blocks/CU,
//   grids >=800 or multi-round. fwd2m/upd1m: 2-cb blocking. fwd3m: och in
//   [0,4). upd2m: 1-cb, grid 800. fwd kernels now hi-only -> 32KB LDS,
//   5 blocks/CU (more TLP; LDS shrinks, occupancy rises).
// XCD-clustered 1-D decode (grids %8==0): cb clusters of 4 per XCD.
// fu3: w4s additive swizzle phys(k)=k+((k>>7)<<2), row 1056 (bank-conflict
//   fix; k0%128<=123 so paired +4 read stays in-block).
// First-iteration aliasing: t1==h1, t2==p2, t3==p3 bit-exactly.

__device__ __forceinline__ float b2f(bf16 v) { return __bfloat162float(v); }
__device__ __forceinline__ bf16  f2b(float v) { return __float2bfloat16(v); }
__device__ __forceinline__ float blo(unsigned u) { return __uint_as_float(u << 16); }
__device__ __forceinline__ float bhi(unsigned u) { return __uint_as_float(u & 0xffff0000u); }
__device__ __forceinline__ unsigned short fbits(float v) {
  union { bf16 b; unsigned short u; } c; c.b = f2b(v); return c.u;
}
__device__ __forceinline__ float ubf(unsigned short u) {
  return __uint_as_float(((unsigned)u) << 16);
}
// async global->LDS, 16B per lane. LDS dest must be wave-uniform base + lane*16.
__device__ __forceinline__ void gld16(const void* g, void* l) {
  __builtin_amdgcn_global_load_lds((const unsigned int*)g, (unsigned int*)l, 16, 0, 0);
}

// ---- weight prep ----
__global__ __launch_bounds__(256) void k_prep(
    const float* __restrict__ W1, const float* __restrict__ W2,
    const float* __restrict__ W3, float* __restrict__ W1t,
    short* __restrict__ W2f, short* __restrict__ W2u,
    short* __restrict__ W3m, short* __restrict__ W3u) {
  int i = blockIdx.x * 256 + threadIdx.x;
  if (i < 4800) {
    int oc = i / 75, k = i % 75;
    W1t[k * 64 + oc] = W1[i];
  }
  if (i < 204800) {
    int oc = i / 1600, k = i % 1600, ic = k / 25, tap = k % 25;
    float w = W2[i];
    unsigned short hi = fbits(w);
    W2f[(tap * 128 + oc) * 64 + (ic ^ ((oc & 7) << 3))] = (short)hi;
    W2u[(tap * 64 + ic) * 128 + (oc ^ ((ic & 7) << 3))] = (short)hi;
  }
  if (i < 294912) {
    int oc = i / 1152, k = i % 1152, ic = k / 9, tap = k % 9;
    float w = W3[i];
    unsigned short hi = fbits(w);
    W3m[(tap * 256 + oc) * 128 + (ic ^ ((oc & 7) << 3))] = (short)hi;
    W3u[(tap * 128 + ic) * 256 + (oc ^ ((ic & 7) << 3))] = (short)hi;
  }
}

// ---- conv1 (LDS-staged, 512 threads): h1T = relu(conv1(x)) ----
// block=(bt,oy), oy in [0,14). Wave w8: oc-group w8&3, h-half w8>>2.
__global__ __launch_bounds__(512, 1) void k_conv1s(
    const float* __restrict__ x, const float* __restrict__ W1t,
    const float* __restrict__ b1, bf16* __restrict__ h1T) {
  __shared__ float xs[480 * 66];  // [f 480 = ic*160+ky*32+x][col 64 (+2 pad)]
  __shared__ float ws[4800];      // [tap 75][oc 64]
  int bt = blockIdx.x, oy = blockIdx.y;
  int tid = threadIdx.x, lane = tid & 63, w8 = tid >> 6;
  int wv = w8 & 3, h = w8 >> 2;
  for (int i = tid; i < 4800; i += 512) ws[i] = W1t[i];
#pragma unroll
  for (int r = 0; r < 15; ++r) {
    int idx = r * 512 + tid;
    int col = idx / 120, q = idx % 120;
    int ic = q / 40, rem = q % 40;
    float4 v = *(const float4*)(x + (size_t)(bt * 64 + col) * 3072 +
                                ic * 1024 + oy * 64 + rem * 4);
    float* d = xs + (ic * 160 + rem * 4) * 66 + col;
    d[0] = v.x;
    d[66] = v.y;
    d[132] = v.z;
    d[198] = v.w;
  }
  __syncthreads();
  int oc0 = wv * 16;
  float acc[7][16];
#pragma unroll
  for (int o = 0; o < 7; ++o)
#pragma unroll
    for (int j = 0; j < 16; ++j) acc[o][j] = b1[oc0 + j];
  for (int ic = 0; ic < 3; ++ic)
    for (int ky = 0; ky < 5; ++ky) {
#pragma unroll
      for (int kx = 0; kx < 5; ++kx) {
        const float* wp = ws + ((ic * 25 + ky * 5 + kx) << 6) + oc0;
        float4 w0 = *(const float4*)(wp);
        float4 w1 = *(const float4*)(wp + 4);
        float4 w2 = *(const float4*)(wp + 8);
        float4 w3 = *(const float4*)(wp + 12);
        const float* xr = xs + (ic * 160 + ky * 32 + kx) * 66 + lane;
        float xv[7];
#pragma unroll
        for (int o = 0; o < 7; ++o) xv[o] = xr[(2 * (h * 7 + o)) * 66];
#pragma unroll
        for (int o = 0; o < 7; ++o) {
          float e = xv[o];
          acc[o][0] += e * w0.x;  acc[o][1] += e * w0.y;
          acc[o][2] += e * w0.z;  acc[o][3] += e * w0.w;
          acc[o][4] += e * w1.x;  acc[o][5] += e * w1.y;
          acc[o][6] += e * w1.z;  acc[o][7] += e * w1.w;
          acc[o][8] += e * w2.x;  acc[o][9] += e * w2.y;
          acc[o][10] += e * w2.z; acc[o][11] += e * w2.w;
          acc[o][12] += e * w3.x; acc[o][13] += e * w3.y;
          acc[o][14] += e * w3.z; acc[o][15] += e * w3.w;
        }
      }
    }
#pragma unroll
  for (int o = 0; o < 7; ++o) {
    int pix = oy * 14 + h * 7 + o;
    size_t tbase = ((size_t)(pix * 32 + bt)) << 12;
#pragma unroll
    for (int q = 0; q < 4; ++q) {
      ushort4 pk;
      pk.x = fbits(fmaxf(acc[o][q * 4 + 0], 0.f));
      pk.y = fbits(fmaxf(acc[o][q * 4 + 1], 0.f));
      pk.z = fbits(fmaxf(acc[o][q * 4 + 2], 0.f));
      pk.w = fbits(fmaxf(acc[o][q * 4 + 3], 0.f));
      int ocr = oc0 + q * 4;
      size_t off = tbase + lane * 64 + (ocr ^ ((lane & 7) << 3));
      *(ushort4*)(h1T + off) = pk;
    }
  }
}

// ---- fwd2 (MFMA, 2-cb, hi-only): p2T = relu(conv2(in1)); fused e2T ----
// grid 400 (1-D): xcd=bid&7, j=bid>>3 (0..49), cbp=xcd*2+(j&1), pos=j>>1
// LDS 32KB -> 5 blocks/CU.
__global__ __launch_bounds__(256) void k_fwd2m(
    const bf16* __restrict__ in1, const short* __restrict__ W2f,
    const float* __restrict__ b2, bf16* __restrict__ p2T,
    const bf16* __restrict__ t2e, bf16* __restrict__ e2T, int einit) {
  __shared__ __align__(16) short As0[8192];     // hi [128 oc][64 ic]
  __shared__ __align__(16) short Bs[2][4096];   // [cb][64 col][64 ic]
  int bid = blockIdx.x;
  int j = bid >> 3;
  int cbp = (bid & 7) * 2 + (j & 1), pos = j >> 1;
  int cb0 = cbp * 2;
  int tid = threadIdx.x, lane = tid & 63, wv = tid >> 6;
  int oy = pos / 5, ox = pos % 5;
  float4v acc[2][2][4];
#pragma unroll
  for (int c = 0; c < 2; ++c)
#pragma unroll
    for (int m = 0; m < 2; ++m)
#pragma unroll
      for (int n = 0; n < 4; ++n) acc[c][m][n] = (float4v){0.f, 0.f, 0.f, 0.f};

  for (int tap = 0; tap < 25; ++tap) {
    int ky = tap / 5, kx = tap % 5;
    int ipix = (2 * oy + ky) * 14 + (2 * ox + kx);
    __syncthreads();
    {
      const uint4* bs0 = (const uint4*)(in1 + (((size_t)(ipix * 32 + cb0)) << 12));
      const uint4* bs1 = (const uint4*)(in1 + (((size_t)(ipix * 32 + cb0 + 1)) << 12));
      uint4* bd = (uint4*)Bs;
      gld16(&bs0[tid], &bd[tid]);
      gld16(&bs0[tid + 256], &bd[tid + 256]);
      gld16(&bs1[tid], &bd[tid + 512]);
      gld16(&bs1[tid + 256], &bd[tid + 768]);
      const uint4* ah = (const uint4*)(W2f + tap * 8192);
      uint4* dh = (uint4*)As0;
#pragma unroll
      for (int p = 0; p < 4; ++p) {
        gld16(&ah[tid + p * 256], &dh[tid + p * 256]);
      }
    }
    __syncthreads();
#pragma unroll
    for (int ks = 0; ks < 2; ++ks) {
      int ic0 = ks * 32 + ((lane >> 4) << 3);
      short8v bfr[2][4];
#pragma unroll
      for (int c = 0; c < 2; ++c)
#pragma unroll
        for (int n = 0; n < 4; ++n) {
          int colv = n * 16 + (lane & 15);
          bfr[c][n] = *(const short8v*)(&Bs[c][0] + colv * 64 + (ic0 ^ ((colv & 7) << 3)));
        }
#pragma unroll
      for (int m = 0; m < 2; ++m) {
        int row = wv * 32 + m * 16 + (lane & 15);
        int aoff = row * 64 + (ic0 ^ ((row & 7) << 3));
        short8v ah = *(const short8v*)(As0 + aoff);
#pragma unroll
        for (int c = 0; c < 2; ++c)
#pragma unroll
          for (int n = 0; n < 4; ++n) {
            acc[c][m][n] = __builtin_amdgcn_mfma_f32_16x16x32_bf16(ah, bfr[c][n], acc[c][m][n], 0, 0, 0);
          }
      }
    }
  }
#pragma unroll
  for (int c = 0; c < 2; ++c) {
    size_t tb2 = ((size_t)(pos * 32 + cb0 + c)) << 13;
#pragma unroll
    for (int m = 0; m < 2; ++m) {
      int ocb = wv * 32 + m * 16 + ((lane >> 4) << 2);
      float4 bv = *(const float4*)(b2 + ocb);
#pragma unroll
      for (int n = 0; n < 4; ++n) {
        int colv = n * 16 + (lane & 15);
        ushort4 pk;
        pk.x = fbits(fmaxf(acc[c][m][n][0] + bv.x, 0.f));
        pk.y = fbits(fmaxf(acc[c][m][n][1] + bv.y, 0.f));
        pk.z = fbits(fmaxf(acc[c][m][n][2] + bv.z, 0.f));
        pk.w = fbits(fmaxf(acc[c][m][n][3] + bv.w, 0.f));
        size_t off = tb2 + colv * 128 + (ocb ^ ((colv & 7) << 3));
        *(ushort4*)(p2T + off) = pk;
        if (einit) {
          ushort4 z = {0, 0, 0, 0};
          *(ushort4*)(e2T + off) = z;
        } else {
          ushort4 tv = *(const ushort4*)(t2e + off);
          ushort4 ev;
          float p0, t0;
          p0 = ubf(pk.x); t0 = ubf(tv.x); ev.x = fbits(p0 > 0.f ? t0 - p0 : 0.f);
          p0 = ubf(pk.y); t0 = ubf(tv.y); ev.y = fbits(p0 > 0.f ? t0 - p0 : 0.f);
          p0 = ubf(pk.z); t0 = ubf(tv.z); ev.z = fbits(p0 > 0.f ? t0 - p0 : 0.f);
          p0 = ubf(pk.w); t0 = ubf(tv.w); ev.w = fbits(p0 > 0.f ? t0 - p0 : 0.f);
          *(ushort4*)(e2T + off) = ev;
        }
      }
    }
  }
}

// ---- upd1 (MFMA, hi-only, 2-cb): g1 = conv2^T(e2T); t1w = upd(t1r) ----
// grid 3136 (1-D): xcd=bid&7, j=bid>>3 (0..391), cbp=xcd*2+(j&1), pix=j>>1
__global__ __launch_bounds__(256) void k_upd1m(
    const bf16* __restrict__ e2T, const short* __restrict__ W2u,
    const bf16* __restrict__ h1T, const bf16* __restrict__ t1r,
    bf16* __restrict__ t1w) {
  __shared__ __align__(16) short As0[8192];    // hi [64 ic][128 oc]
  __shared__ __align__(16) short Es[2][8192];  // [cb][64 col][128 oc]
  int bid = blockIdx.x;
  int j = bid >> 3;
  int cbp = (bid & 7) * 2 + (j & 1), pix = j >> 1;
  int cb0 = cbp * 2;
  int tid = threadIdx.x, lane = tid & 63, wv = tid >> 6;
  int iy = pix / 14, ix = pix % 14;
  float4v acc[2][4];
#pragma unroll
  for (int c = 0; c < 2; ++c)
#pragma unroll
    for (int n = 0; n < 4; ++n) acc[c][n] = (float4v){0.f, 0.f, 0.f, 0.f};

  for (int ky = iy & 1; ky <= 4; ky += 2) {
    int oy = (iy - ky) >> 1;
    if (oy < 0 || oy > 4) continue;
    for (int kx = ix & 1; kx <= 4; kx += 2) {
      int ox = (ix - kx) >> 1;
      if (ox < 0 || ox > 4) continue;
      int erow = oy * 5 + ox, tap = ky * 5 + kx;
      __syncthreads();
      {
        const uint4* es0 = (const uint4*)(e2T + (((size_t)(erow * 32 + cb0)) << 13));
        const uint4* es1 = (const uint4*)(e2T + (((size_t)(erow * 32 + cb0 + 1)) << 13));
        uint4* ed = (uint4*)Es;
        const uint4* ah = (const uint4*)(W2u + tap * 8192);
        uint4* dh = (uint4*)As0;
#pragma unroll
        for (int p = 0; p < 4; ++p) {
          gld16(&es0[tid + p * 256], &ed[tid + p * 256]);
          gld16(&es1[tid + p * 256], &ed[tid + p * 256 + 1024]);
          gld16(&ah[tid + p * 256], &dh[tid + p * 256]);
        }
      }
      __syncthreads();
#pragma unroll
      for (int ks = 0; ks < 4; ++ks) {
        int oc0 = ks * 32 + ((lane >> 4) << 3);
        int row = wv * 16 + (lane & 15);
        int aoff = row * 128 + (oc0 ^ ((row & 7) << 3));
        short8v ah = *(const short8v*)(As0 + aoff);
#pragma unroll
        for (int c = 0; c < 2; ++c)
#pragma unroll
          for (int n = 0; n < 4; ++n) {
            int colv = n * 16 + (lane & 15);
            short8v ef = *(const short8v*)(&Es[c][0] + colv * 128 + (oc0 ^ ((colv & 7) << 3)));
            acc[c][n] = __builtin_amdgcn_mfma_f32_16x16x32_bf16(ah, ef, acc[c][n], 0, 0, 0);
          }
      }
    }
  }
  int icb = wv * 16 + ((lane >> 4) << 2);
#pragma unroll
  for (int c = 0; c < 2; ++c) {
    size_t tb1 = ((size_t)(pix * 32 + cb0 + c)) << 12;
#pragma unroll
    for (int n = 0; n < 4; ++n) {
      int colv = n * 16 + (lane & 15);
      size_t off = tb1 + colv * 64 + (icb ^ ((colv & 7) << 3));
      ushort4 tv = *(const ushort4*)(t1r + off);
      ushort4 hv = *(const ushort4*)(h1T + off);
      ushort4 rp;
      float t0, h0;
      t0 = ubf(tv.x); h0 = ubf(hv.x);
      rp.x = fbits(t0 - 0.07f * (t0 - h0) + 0.07f * acc[c][n][0]);
      t0 = ubf(tv.y); h0 = ubf(hv.y);
      rp.y = fbits(t0 - 0.07f * (t0 - h0) + 0.07f * acc[c][n][1]);
      t0 = ubf(tv.z); h0 = ubf(hv.z);
      rp.z = fbits(t0 - 0.07f * (t0 - h0) + 0.07f * acc[c][n][2]);
      t0 = ubf(tv.w); h0 = ubf(hv.w);
      rp.w = fbits(t0 - 0.07f * (t0 - h0) + 0.07f * acc[c][n][3]);
      *(ushort4*)(t1w + off) = rp;
    }
  }
}

// ---- fwd3 (MFMA, hi-only): p3T = relu(conv3(in2)); fused e3T ----
// grid 512 (1-D): xcd=bid&7, j=bid>>3, cb=xcd*4+(j&3), r=j>>2, pos=r&3, och=r>>2
// LDS 32KB -> 5 blocks/CU.
__global__ __launch_bounds__(256) void k_fwd3m(
    const bf16* __restrict__ in2, const short* __restrict__ W3m,
    const float* __restrict__ b3, bf16* __restrict__ p3T,
    const bf16* __restrict__ t3e, bf16* __restrict__ e3T, int einit) {
  __shared__ __align__(16) short As0[8192];  // hi [64 oc][128 ic]
  __shared__ __align__(16) short Bs[8192];   // [64 col][128 ic]
  int bid = blockIdx.x;
  int j = bid >> 3;
  int cb = (bid & 7) * 4 + (j & 3);
  int r = j >> 2;
  int pos = r & 3, och = r >> 2;
  int tid = threadIdx.x, lane = tid & 63, wv = tid >> 6;
  int oy = pos >> 1, ox = pos & 1;
  float4v acc[4];
#pragma unroll
  for (int n = 0; n < 4; ++n) acc[n] = (float4v){0.f, 0.f, 0.f, 0.f};

  for (int tap = 0; tap < 9; ++tap) {
    int ky = tap / 3, kx = tap % 3;
    int irow = (2 * oy + ky) * 5 + (2 * ox + kx);
    __syncthreads();
    {
      const uint4* bs = (const uint4*)(in2 + (((size_t)(irow * 32 + cb)) << 13));
      uint4* bd = (uint4*)Bs;
#pragma unroll
      for (int p = 0; p < 4; ++p) gld16(&bs[tid + p * 256], &bd[tid + p * 256]);
      const uint4* ah = (const uint4*)(W3m + ((size_t)tap * 256 + och * 64) * 128);
      uint4* dh = (uint4*)As0;
#pragma unroll
      for (int p = 0; p < 4; ++p) {
        gld16(&ah[tid + p * 256], &dh[tid + p * 256]);
      }
    }
    __syncthreads();
#pragma unroll
    for (int ks = 0; ks < 4; ++ks) {
      int ic0 = ks * 32 + ((lane >> 4) << 3);
      short8v bfr[4];
#pragma unroll
      for (int n = 0; n < 4; ++n) {
        int colv = n * 16 + (lane & 15);
        bfr[n] = *(const short8v*)(Bs + colv * 128 + (ic0 ^ ((colv & 7) << 3)));
      }
      int row = wv * 16 + (lane & 15);
      int aoff = row * 128 + (ic0 ^ ((row & 7) << 3));
      short8v ah = *(const short8v*)(As0 + aoff);
#pragma unroll
      for (int n = 0; n < 4; ++n) {
        acc[n] = __builtin_amdgcn_mfma_f32_16x16x32_bf16(ah, bfr[n], acc[n], 0, 0, 0);
      }
    }
  }
  size_t tb3 = ((size_t)(pos * 32 + cb)) << 14;
  int ocg = och * 64 + wv * 16 + ((lane >> 4) << 2);
  float4 bv = *(const float4*)(b3 + ocg);
#pragma unroll
  for (int n = 0; n < 4; ++n) {
    int colv = n * 16 + (lane & 15);
    ushort4 pk;
    pk.x = fbits(fmaxf(acc[n][0] + bv.x, 0.f));
    pk.y = fbits(fmaxf(acc[n][1] + bv.y, 0.f));
    pk.z = fbits(fmaxf(acc[n][2] + bv.z, 0.f));
    pk.w = fbits(fmaxf(acc[n][3] + bv.w, 0.f));
    size_t off = tb3 + colv * 256 + (ocg ^ ((colv & 7) << 3));
    *(ushort4*)(p3T + off) = pk;
    if (einit) {
      ushort4 z = {0, 0, 0, 0};
      *(ushort4*)(e3T + off) = z;
    } else {
      ushort4 tv = *(const ushort4*)(t3e + off);
      ushort4 ev;
      float p0, t0;
      p0 = ubf(pk.x); t0 = ubf(tv.x); ev.x = fbits(p0 > 0.f ? t0 - p0 : 0.f);
      p0 = ubf(pk.y); t0 = ubf(tv.y); ev.y = fbits(p0 > 0.f ? t0 - p0 : 0.f);
      p0 = ubf(pk.z); t0 = ubf(tv.z); ev.z = fbits(p0 > 0.f ? t0 - p0 : 0.f);
      p0 = ubf(pk.w); t0 = ubf(tv.w); ev.w = fbits(p0 > 0.f ? t0 - p0 : 0.f);
      *(ushort4*)(e3T + off) = ev;
    }
  }
}

// ---- upd2 (MFMA, hi-only): g2 = conv3^T(e3T); t2w = upd(t2r) ----
// grid 800 (1-D): xcd=bid&7, j=bid>>3, cb=xcd*4+(j&3), pix=j>>2
__global__ __launch_bounds__(256) void k_upd2m(
    const bf16* __restrict__ e3T, const bf16* __restrict__ p2T,
    const short* __restrict__ W3u, const bf16* __restrict__ t2r,
    bf16* __restrict__ t2w) {
  __shared__ __align__(16) short Es[8192];    // [64 col][128 oc_local]
  __shared__ __align__(16) short As0[16384];  // hi [128 ic][128 oc_local]
  int bid = blockIdx.x;
  int j = bid >> 3;
  int cb = (bid & 7) * 4 + (j & 3), pix = j >> 2;
  int tid = threadIdx.x, lane = tid & 63, wv = tid >> 6;
  int iy = pix / 5, ix = pix % 5;
  float4v acc[2][4];
#pragma unroll
  for (int m = 0; m < 2; ++m)
#pragma unroll
    for (int n = 0; n < 4; ++n) acc[m][n] = (float4v){0.f, 0.f, 0.f, 0.f};

  for (int ky = iy & 1; ky <= 2; ky += 2) {
    int oy = (iy - ky) >> 1;
    if (oy < 0 || oy > 1) continue;
    for (int kx = ix & 1; kx <= 2; kx += 2) {
      int ox = (ix - kx) >> 1;
      if (ox < 0 || ox > 1) continue;
      int erow = oy * 2 + ox, tap = ky * 3 + kx;
      for (int occ = 0; occ < 2; ++occ) {
        __syncthreads();
        {
          size_t tb = ((size_t)(erow * 32 + cb)) << 14;
          uint4* ed = (uint4*)Es;
#pragma unroll
          for (int p = 0; p < 4; ++p) {
            int fi = tid + p * 256;
            int colr = fi >> 4, q = fi & 15;
            size_t g = tb + colr * 256 + occ * 128 + q * 8;
            gld16(e3T + g, &ed[fi]);
          }
          uint4* dh = (uint4*)As0;
#pragma unroll
          for (int p = 0; p < 8; ++p) {
            int fi = tid + p * 256;
            int icr = fi >> 4, q = fi & 15;
            size_t srcoff = ((size_t)(tap * 128 + icr)) * 256 + occ * 128 + q * 8;
            gld16(W3u + srcoff, &dh[fi]);
          }
        }
        __syncthreads();
#pragma unroll
        for (int ks = 0; ks < 4; ++ks) {
          int oc0 = ks * 32 + ((lane >> 4) << 3);
          short8v efr[4];
#pragma unroll
          for (int n = 0; n < 4; ++n) {
            int colv = n * 16 + (lane & 15);
            efr[n] = *(const short8v*)(Es + colv * 128 + (oc0 ^ ((colv & 7) << 3)));
          }
#pragma unroll
          for (int m = 0; m < 2; ++m) {
            int icr = wv * 32 + m * 16 + (lane & 15);
            int aoff = icr * 128 + (oc0 ^ ((icr & 7) << 3));
            short8v ah = *(const short8v*)(As0 + aoff);
#pragma unroll
            for (int n = 0; n < 4; ++n) {
              acc[m][n] = __builtin_amdgcn_mfma_f32_16x16x32_bf16(ah, efr[n], acc[m][n], 0, 0, 0);
            }
          }
        }
      }
    }
  }
  size_t tb2 = ((size_t)(pix * 32 + cb)) << 13;
#pragma unroll
  for (int m = 0; m < 2; ++m) {
    int icr = wv * 32 + m * 16 + ((lane >> 4) << 2);
#pragma unroll
    for (int n = 0; n < 4; ++n) {
      int colv = n * 16 + (lane & 15);
      size_t off = tb2 + colv * 128 + (icr ^ ((colv & 7) << 3));
      ushort4 tv = *(const ushort4*)(t2r + off);
      ushort4 pv = *(const ushort4*)(p2T + off);
      ushort4 rp;
      float t0, p0;
      t0 = ubf(tv.x); p0 = ubf(pv.x);
      rp.x = fbits(t0 - 0.07f * (t0 - p0) + 0.07f * acc[m][n][0]);
      t0 = ubf(tv.y); p0 = ubf(pv.y);
      rp.y = fbits(t0 - 0.07f * (t0 - p0) + 0.07f * acc[m][n][1]);
      t0 = ubf(tv.z); p0 = ubf(pv.z);
      rp.z = fbits(t0 - 0.07f * (t0 - p0) + 0.07f * acc[m][n][2]);
      t0 = ubf(tv.w); p0 = ubf(pv.w);
      rp.w = fbits(t0 - 0.07f * (t0 - p0) + 0.07f * acc[m][n][3]);
      *(ushort4*)(t2w + off) = rp;
    }
  }
}

// ---- fu3: p4 = t3r @ W4^T + b4 (all-lane butterfly); softmax; e4;
//      g3 = e4 @ W4; t3w = upd(t3r).
//      w4s bank-conflict-free: phys(k) = k + ((k>>7)<<2), row stride 1056. ----
__global__ __launch_bounds__(256) void k_fu3(
    const float* __restrict__ gt, const float* __restrict__ W4,
    const float* __restrict__ b4, const bf16* __restrict__ p3T,
    const bf16* __restrict__ t3r, bf16* __restrict__ t3w) {
  __shared__ __align__(16) float w4s[10560];  // 10 rows x 1056 (swizzled)
  int tid = threadIdx.x;
  for (int i = tid; i < 10240; i += 256) {
    int o = i >> 10, k = i & 1023;
    w4s[o * 1056 + k + ((k >> 7) << 2)] = W4[i];
  }
  __syncthreads();
  int c = blockIdx.x * 8 + (tid >> 5);
  int cb = c >> 6, colL = c & 63, subk = tid & 31;
  int pos = subk & 3, ch0 = (subk >> 2) * 32;
  int xc = (colL & 7) << 3;
  size_t boff = (((size_t)(pos * 32 + cb)) << 14) + colL * 256 + ch0;
  const bf16* trd = t3r + boff;
  const bf16* pb = p3T + boff;
  uint4 tq[4];
#pragma unroll
  for (int q = 0; q < 4; ++q) tq[q] = *(const uint4*)(trd + q * 8);
  float acc[10] = {};
#pragma unroll
  for (int q = 0; q < 4; ++q) {
    unsigned wds[4] = {tq[q].x, tq[q].y, tq[q].z, tq[q].w};
    int chb = (ch0 + q * 8) ^ xc;
#pragma unroll
    for (int h = 0; h < 4; ++h) {
      float v0 = blo(wds[h]), v1 = bhi(wds[h]);
      int k0 = (chb + 2 * h) * 4 + pos;
      int ks = k0 + ((k0 >> 7) << 2);  // k0%128<=123 so +4 stays in-block
#pragma unroll
      for (int o = 0; o < 10; ++o)
        acc[o] += v0 * w4s[o * 1056 + ks] + v1 * w4s[o * 1056 + ks + 4];
    }
  }
#pragma unroll
  for (int off = 16; off > 0; off >>= 1)
#pragma unroll
    for (int o = 0; o < 10; ++o) acc[o] += __shfl_xor(acc[o], off, 32);
  float pv[10], m = -1e30f;
#pragma unroll
  for (int o = 0; o < 10; ++o) {
    pv[o] = acc[o] + b4[o];
    m = fmaxf(m, pv[o]);
  }
  float s = 0.f;
#pragma unroll
  for (int o = 0; o < 10; ++o) {
    pv[o] = __expf(pv[o] - m);
    s += pv[o];
  }
  float inv = 1.f / s;
  float e4[10];
#pragma unroll
  for (int o = 0; o < 10; ++o)
    e4[o] = (gt[(size_t)c * 10 + o] - pv[o] * inv) * 0.5f;
  bf16* tb = t3w + boff;
#pragma unroll
  for (int q = 0; q < 4; ++q) {
    uint4 pq = *(const uint4*)(pb + q * 8);
    unsigned tw[4] = {tq[q].x, tq[q].y, tq[q].z, tq[q].w};
    unsigned pw[4] = {pq.x, pq.y, pq.z, pq.w};
    int chb = (ch0 + q * 8) ^ xc;
    unsigned ro[4];
#pragma unroll
    for (int h = 0; h < 4; ++h) {
      int k0 = (chb + 2 * h) * 4 + pos;
      int ks = k0 + ((k0 >> 7) << 2);
      float g0 = 0.f, g1 = 0.f;
#pragma unroll
      for (int o = 0; o < 10; ++o) {
        g0 += e4[o] * w4s[o * 1056 + ks];
        g1 += e4[o] * w4s[o * 1056 + ks + 4];
      }
      float t0 = blo(tw[h]), p0 = blo(pw[h]);
      float t1 = bhi(tw[h]), p1 = bhi(pw[h]);
      float r0 = t0 - 0.07f * (t0 - p0) + 0.07f * g0;
      float r1 = t1 - 0.07f * (t1 - p1) + 0.07f * g1;
      ro[h] = (unsigned)fbits(r0) | ((unsigned)fbits(r1) << 16);
    }
    uint4 rv = {ro[0], ro[1], ro[2], ro[3]};
    *(uint4*)(tb + q * 8) = rv;
  }
}

// ---- k_tr1: t1 section gather (contiguous slab reads, LDS rotate) ----
__global__ __launch_bounds__(256) void k_tr1(
    const bf16* __restrict__ t1T, float* __restrict__ out) {
  __shared__ short lds[2 * 64 * 224];
  int cb = blockIdx.x, c0 = blockIdx.y * 2;
  int tid = threadIdx.x;
  for (int i = tid; i < 3136; i += 256) {
    int pix = i >> 4, q = i & 15;
    int colL = q >> 3, chb = (q & 7) << 3;
    int col = c0 + colL;
    uint4 v = *(const uint4*)(t1T + (((size_t)(pix * 32 + cb)) << 12) + col * 64 + chb);
    int icb = chb ^ ((col & 7) << 3);
    int posX = pix ^ (((icb >> 3) & 7) << 2);
    short* d = lds + (colL * 64 + icb) * 224 + posX;
    const short* vs = (const short*)&v;
#pragma unroll
    for (int j = 0; j < 8; ++j) d[j * 224] = vs[j];
  }
  __syncthreads();
  for (int i = tid; i < 6272; i += 256) {
    int colL = i / 3136, m = i % 3136;
    int ic = m / 49, pp = m % 49;
    int posX = (pp * 4) ^ (((ic >> 3) & 7) << 2);
    const short* s = lds + (colL * 64 + ic) * 224 + posX;
    float4 o;
    o.x = ubf((unsigned short)s[0]);
    o.y = ubf((unsigned short)s[1]);
    o.z = ubf((unsigned short)s[2]);
    o.w = ubf((unsigned short)s[3]);
    *(float4*)(out + ((size_t)(cb * 64 + c0 + colL)) * 16768 + m * 4) = o;
  }
}

// ---- k_tr2: t2 section gather ----
__global__ __launch_bounds__(256) void k_tr2(
    const bf16* __restrict__ t2T, float* __restrict__ out) {
  __shared__ short lds[4 * 128 * 32];
  int cb = blockIdx.x, c0 = blockIdx.y * 4;
  int tid = threadIdx.x;
  for (int i = tid; i < 1600; i += 256) {
    int pos = i >> 6, q = i & 63;
    int colL = q >> 4, chb = (q & 15) << 3;
    int col = c0 + colL;
    uint4 v = *(const uint4*)(t2T + (((size_t)(pos * 32 + cb)) << 13) + col * 128 + chb);
    int ocb = chb ^ ((col & 7) << 3);
    int posX = pos ^ (((ocb >> 3) & 7) << 2);
    short* d = lds + (colL * 128 + ocb) * 32 + posX;
    const short* vs = (const short*)&v;
#pragma unroll
    for (int j = 0; j < 8; ++j) d[j * 32] = vs[j];
  }
  __syncthreads();
  for (int i = tid; i < 3200; i += 256) {
    int colL = i / 800, m = i % 800;
    int f0 = m * 4;
    float4 o;
    float* po = &o.x;
#pragma unroll
    for (int t = 0; t < 4; ++t) {
      int f = f0 + t;
      int oc = f / 25, pos = f % 25;
      int posX = pos ^ (((oc >> 3) & 7) << 2);
      po[t] = ubf((unsigned short)lds[(colL * 128 + oc) * 32 + posX]);
    }
    *(float4*)(out + ((size_t)(cb * 64 + c0 + colL)) * 16768 + 12544 + f0) = o;
  }
}

// ---- k_tr3: t3 section gather, register transpose ----
__global__ __launch_bounds__(256) void k_tr3(
    const bf16* __restrict__ t3T, float* __restrict__ out) {
  int tid = threadIdx.x;
  int sample = blockIdx.x * 8 + (tid >> 5);
  int cb = sample >> 6, col = sample & 63;
  int chb = (tid & 31) << 3;
  int icb = chb ^ ((col & 7) << 3);
  uint4 v[4];
#pragma unroll
  for (int pos = 0; pos < 4; ++pos)
    v[pos] = *(const uint4*)(t3T + (((size_t)(pos * 32 + cb)) << 14) + col * 256 + chb);
  const unsigned short* s0 = (const unsigned short*)&v[0];
  const unsigned short* s1 = (const unsigned short*)&v[1];
  const unsigned short* s2 = (const unsigned short*)&v[2];
  const unsigned short* s3 = (const unsigned short*)&v[3];
  float* ob = out + (size_t)sample * 16768 + 15744 + icb * 4;
#pragma unroll
  for (int j = 0; j < 8; ++j) {
    float4 o;
    o.x = ubf(s0[j]);
    o.y = ubf(s1[j]);
    o.z = ubf(s2[j]);
    o.w = ubf(s3[j]);
    *(float4*)(ob + j * 4) = o;
  }
}

extern "C" void kernel_launch(void* const* d_in, const int* in_sizes, int n_in,
                              void* d_out, int out_size, void* d_ws,
                              size_t ws_size, hipStream_t stream) {
  const float* x  = (const float*)d_in[0];
  const float* gt = (const float*)d_in[1];
  const float* W1 = (const float*)d_in[2];
  const float* b1 = (const float*)d_in[3];
  const float* W2 = (const float*)d_in[4];
  const float* b2 = (const float*)d_in[5];
  const float* W3 = (const float*)d_in[6];
  const float* b3 = (const float*)d_in[7];
  const float* W4 = (const float*)d_in[8];
  const float* b4 = (const float*)d_in[9];
  float* out = (float*)d_out;

  bf16* h1T = (bf16*)d_ws;
  bf16* t1T = h1T + 25690112ull;
  bf16* t2T = t1T + 25690112ull;
  bf16* p2T = t2T + 6553600ull;
  bf16* t3T = p2T + 6553600ull;
  bf16* p3T = t3T + 2097152ull;
  float* p4f = (float*)(p3T + 2097152ull);  // unused (kept for layout)
  float* W1t = p4f + 20480;
  short* W3m = (short*)(W1t + 4800);
  short* W3u = W3m + 589824;
  short* W2f = W3u + 589824;
  short* W2u = W2f + 409600;
  // e2T/e3T (13.1 + 4.2 MB bf16) live in d_out (134 MB), dead until k_tr*.
  bf16* e2T = (bf16*)out;
  bf16* e3T = e2T + 6553600ull;

  dim3 blk(256);

  k_prep<<<1152, blk, 0, stream>>>(W1, W2, W3, W1t, W2f, W2u, W3m, W3u);
  k_conv1s<<<dim3(32, 14), dim3(512), 0, stream>>>(x, W1t, b1, h1T);
  k_fwd2m<<<400, blk, 0, stream>>>(h1T, W2f, b2, p2T, p2T, e2T, 1);
  k_fwd3m<<<512, blk, 0, stream>>>(p2T, W3m, b3, p3T, p3T, e3T, 1);

  for (int it = 0; it < 25; ++it) {
    const bf16* t1r = (it == 0) ? h1T : t1T;
    const bf16* t2r = (it == 0) ? p2T : t2T;
    const bf16* t3r = (it == 0) ? p3T : t3T;
    k_upd1m<<<3136, blk, 0, stream>>>(e2T, W2u, h1T, t1r, t1T);
    k_upd2m<<<800, blk, 0, stream>>>(e3T, p2T, W3u, t2r, t2T);
    k_fu3<<<256, blk, 0, stream>>>(gt, W4, b4, p3T, t3r, t3T);
    if (it < 24) {
      k_fwd2m<<<400, blk, 0, stream>>>(t1T, W2f, b2, p2T, t2T, e2T, 0);
      k_fwd3m<<<512, blk, 0, stream>>>(t2T, W3m, b3, p3T, t3T, e3T, 0);
    }
  }
  k_tr1<<<dim3(32, 32), blk, 0, stream>>>(t1T, out);
  k_tr2<<<dim3(32, 16), blk, 0, stream>>>(t2T, out);
  k_tr3<<<256, blk, 0, stream>>>(t3T, out);
}